// Round 16
// baseline (530.633 us; speedup 1.0000x reference)
//
#include <hip/hip_runtime.h>
#include <hip/hip_bf16.h>
#include <cmath>

typedef __bf16 bf16x8 __attribute__((ext_vector_type(8)));
typedef __bf16 bf16x4 __attribute__((ext_vector_type(4)));
typedef float  f32x4  __attribute__((ext_vector_type(4)));
typedef unsigned int u32;
typedef u32 u32x4 __attribute__((ext_vector_type(4)));

#define AS1 __attribute__((address_space(1)))
#define AS3 __attribute__((address_space(3)))
#define GLDS16(gp, lp) __builtin_amdgcn_global_load_lds((AS1 void*)(gp), (AS3 void*)(lp), 16, 0, 0)

#define B_DIM 2
#define S_LEN 2048
#define HIDDEN 4096
#define NHEADS 32
#define NKV 8
#define HDIM 128
#define QSZ 4096
#define KVSZ 1024
#define QKVSZ 6144
#define GK 4096                /* K of both GEMMs */
#define ATT_SCALE 0.0078125f   /* 1/128, folded into Qb at RoPE time */
#define L2E 1.4426950408889634f

// ---------------- merged f32 -> bf16 conversion (3 buffers, grid-stride) ----------------
__global__ __launch_bounds__(256) void conv3_f32_bf16(const float* __restrict__ i0, __bf16* __restrict__ o0, int n0,
                                                      const float* __restrict__ i1, __bf16* __restrict__ o1, int n1,
                                                      const float* __restrict__ i2, __bf16* __restrict__ o2, int n2) {
    const int total = n0 + n1 + n2;
    for (int idx = blockIdx.x * 256 + threadIdx.x; idx < total; idx += gridDim.x * 256) {
        const float* in; __bf16* out; int j = idx;
        if (j < n0) { in = i0; out = o0; }
        else if ((j -= n0) < n1) { in = i1; out = o1; }
        else { j -= n1; in = i2; out = o2; }
        float4 v = ((const float4*)in)[j];
        bf16x4 o;
        o[0] = (__bf16)v.x; o[1] = (__bf16)v.y; o[2] = (__bf16)v.z; o[3] = (__bf16)v.w;
        ((bf16x4*)out)[j] = o;
    }
}

// ---------------- RoPE cos/sin table: [pos][i], i<64 ----------------
__global__ __launch_bounds__(256) void rope_table_kernel(float* __restrict__ ct,
                                                         float* __restrict__ st) {
    int idx = blockIdx.x * 256 + threadIdx.x;   // S_LEN*64 entries
    int p = idx >> 6, i = idx & 63;
    float inv = expf(-(float)i * (9.210340371976184f / 64.0f));
    float freq = (float)p * inv;
    float s, c;
    sincosf(freq, &s, &c);
    ct[idx] = c; st[idx] = s;
}

// ---------------- 256x256 4-phase/K-tile GEMM (R15 schedule) + optional split-K via blockIdx.z ----------------
// Each z-plane computes Tloc K-tiles starting at z*Tloc, into C + z*zstride.
template<typename OUT>
__global__ __launch_bounds__(512, 2) void gemm256(const __bf16* __restrict__ A,
                                                  const __bf16* __restrict__ B,
                                                  OUT* __restrict__ C,
                                                  int N, int Tloc, size_t zstride) {
    __shared__ __bf16 Asm[2 * 16384 + 2 * 16384];   // A: 2 slots x 32KB, B: 2 slots x 32KB
    char* Bbase = (char*)Asm + 65536;

    const int tid = threadIdx.x;
    const int w = tid >> 6, l = tid & 63;
    const int l15 = l & 15, l4 = l >> 4;
    const int wr = w >> 2, wc = w & 3;

    const int nwg = gridDim.x * gridDim.y;
    const int orig = blockIdx.y * gridDim.x + blockIdx.x;
    const int swz = (orig & 7) * (nwg >> 3) + (orig >> 3);
    const int bx = swz % gridDim.x, by = swz / gridDim.x;
    const int m0 = by * 256, n0 = bx * 256;

    const int kt0 = blockIdx.z * Tloc;
    const __bf16* Ag = A + (size_t)m0 * GK + (size_t)kt0 * 64;
    const __bf16* Bg = B + (size_t)n0 * GK + (size_t)kt0 * 64;
    OUT* Cz = C + (size_t)blockIdx.z * zstride;

#define STAGE_AQ(q, tile) do {                                                  \
        int c_ = (q) * 512 + tid;                                               \
        int r_ = c_ >> 3;                                                       \
        int jg_ = (tid & 7) ^ (r_ & 7);                                         \
        GLDS16(Ag + (size_t)r_ * GK + (tile) * 64 + jg_ * 8,                    \
               (char*)Asm + ((tile) & 1) * 32768 + c_ * 16);                    \
    } while (0)
#define STAGE_BS(s, tile) do {                                                  \
        _Pragma("unroll")                                                       \
        for (int i_ = 0; i_ < 2; ++i_) {                                        \
            int v_ = i_ * 512 + tid;                                            \
            int r_ = (v_ >> 8) * 64 + (s) * 32 + ((v_ >> 3) & 31);              \
            int jg_ = (v_ & 7) ^ (r_ & 7);                                      \
            int c_ = r_ * 8 + (v_ & 7);                                         \
            GLDS16(Bg + (size_t)r_ * GK + (tile) * 64 + jg_ * 8,                \
                   Bbase + ((tile) & 1) * 32768 + c_ * 16);                     \
        }                                                                       \
    } while (0)

#define LOAD_A(DST, MH) do {                                                    \
        _Pragma("unroll")                                                       \
        for (int m2 = 0; m2 < 4; ++m2) {                                        \
            int row = wr * 128 + ((MH) * 4 + m2) * 16 + l15;                    \
            _Pragma("unroll")                                                   \
            for (int kk = 0; kk < 2; ++kk) {                                    \
                int j = (kk * 4 + l4) ^ (row & 7);                              \
                DST[m2][kk] = *(const bf16x8*)(Als + row * 64 + j * 8);         \
            }                                                                   \
        }                                                                       \
    } while (0)
#define LOAD_B(DST, NH) do {                                                    \
        _Pragma("unroll")                                                       \
        for (int n2 = 0; n2 < 2; ++n2) {                                        \
            int row = wc * 64 + ((NH) * 2 + n2) * 16 + l15;                     \
            _Pragma("unroll")                                                   \
            for (int kk = 0; kk < 2; ++kk) {                                    \
                int j = (kk * 4 + l4) ^ (row & 7);                              \
                DST[n2][kk] = *(const bf16x8*)(Bls + row * 64 + j * 8);         \
            }                                                                   \
        }                                                                       \
    } while (0)
#define MFMA_QUAD(AF, BF, MI0, NI0)                                             \
    _Pragma("unroll")                                                           \
    for (int m2 = 0; m2 < 4; ++m2)                                              \
        _Pragma("unroll")                                                       \
        for (int n2 = 0; n2 < 2; ++n2)                                          \
            _Pragma("unroll")                                                   \
            for (int kk = 0; kk < 2; ++kk)                                      \
                acc[(MI0) + m2][(NI0) + n2] =                                   \
                    __builtin_amdgcn_mfma_f32_16x16x32_bf16(                    \
                        AF[m2][kk], BF[n2][kk], acc[(MI0) + m2][(NI0) + n2], 0, 0, 0);

    f32x4 acc[8][4] = {};

    const int T = Tloc;
    STAGE_AQ(0, 0); STAGE_AQ(1, 0); STAGE_AQ(2, 0); STAGE_AQ(3, 0);
    STAGE_BS(0, 0); STAGE_BS(1, 0);
    STAGE_AQ(0, 1); STAGE_AQ(2, 1); STAGE_BS(0, 1);
    asm volatile("s_waitcnt vmcnt(4)" ::: "memory");
    __builtin_amdgcn_s_barrier();

    for (int t = 0; t < T; ++t) {
        const __bf16* Als = Asm + (t & 1) * 16384;
        const __bf16* Bls = (__bf16*)Bbase + (t & 1) * 16384;
        bf16x8 af0[4][2], af1[4][2], bfr[2][2];
        // ---- ph0: MH0 x NH0 ---- (af0 loaded once, lives through ph1)
        LOAD_A(af0, 0);
        LOAD_B(bfr, 0);
        if (t + 1 < T) { STAGE_AQ(1, t + 1); STAGE_AQ(3, t + 1); }
        __builtin_amdgcn_s_barrier();
        __builtin_amdgcn_s_setprio(1);
        MFMA_QUAD(af0, bfr, 0, 0);
        __builtin_amdgcn_s_setprio(0);
        __builtin_amdgcn_s_barrier();
        // ---- ph1: MH0 x NH1 ---- (reuse af0)
        LOAD_B(bfr, 1);
        if (t + 1 < T) STAGE_BS(1, t + 1);
        __builtin_amdgcn_s_barrier();
        __builtin_amdgcn_s_setprio(1);
        MFMA_QUAD(af0, bfr, 0, 2);
        __builtin_amdgcn_s_setprio(0);
        __builtin_amdgcn_s_barrier();
        // ---- ph2: MH1 x NH0 ---- (af1 loaded once, lives through ph3)
        LOAD_A(af1, 1);
        LOAD_B(bfr, 0);
        if (t + 2 < T) { STAGE_AQ(0, t + 2); STAGE_AQ(2, t + 2); }
        __builtin_amdgcn_s_barrier();
        __builtin_amdgcn_s_setprio(1);
        MFMA_QUAD(af1, bfr, 4, 0);
        __builtin_amdgcn_s_setprio(0);
        __builtin_amdgcn_s_barrier();
        // ---- ph3: MH1 x NH1 ---- (reuse af1)
        LOAD_B(bfr, 1);
        if (t + 2 < T) STAGE_BS(0, t + 2);
        __builtin_amdgcn_s_barrier();
        __builtin_amdgcn_s_setprio(1);
        MFMA_QUAD(af1, bfr, 4, 2);
        __builtin_amdgcn_s_setprio(0);
        if (t + 2 < T)      { asm volatile("s_waitcnt vmcnt(4)" ::: "memory"); }
        else if (t + 1 < T) { asm volatile("s_waitcnt vmcnt(0)" ::: "memory"); }
        __builtin_amdgcn_s_barrier();
    }
#undef MFMA_QUAD
#undef LOAD_A
#undef LOAD_B
#undef STAGE_AQ
#undef STAGE_BS

#pragma unroll
    for (int mi = 0; mi < 8; ++mi)
#pragma unroll
        for (int ni = 0; ni < 4; ++ni)
#pragma unroll
            for (int r = 0; r < 4; ++r)
                Cz[(size_t)(m0 + wr * 128 + mi * 16 + l4 * 4 + r) * N
                   + n0 + wc * 64 + ni * 16 + l15] = (OUT)acc[mi][ni][r];
}

// ---------------- RoPE apply: qkv = P0+P1 (bf16 partials) -> Q (pre-scaled), K bf16 ----------------
__global__ __launch_bounds__(256) void rope_kernel(const __bf16* __restrict__ qkv0,
                                                   const __bf16* __restrict__ qkv1,
                                                   const int* __restrict__ pos,
                                                   const float* __restrict__ ct,
                                                   const float* __restrict__ st,
                                                   __bf16* __restrict__ Qb,
                                                   __bf16* __restrict__ Kb) {
    const int tid = threadIdx.x;
    const int tok = blockIdx.x;                 // 0..B*S-1
    const int b = tok >> 11, s = tok & 2047;
    const int p = pos[tok];
    const __bf16* b0 = qkv0 + (size_t)tok * QKVSZ;
    const __bf16* b1 = qkv1 + (size_t)tok * QKVSZ;
    const float* cb = ct + (size_t)p * 64;
    const float* sb = st + (size_t)p * 64;
    for (int idx = tid; idx < 2560; idx += 256) {   // (32+8)*64 pairs
        int head = idx >> 6, i = idx & 63;
        float c = cb[i], sn = sb[i];
        if (head < 32) {
            float x1 = (float)b0[head * HDIM + i]      + (float)b1[head * HDIM + i];
            float x2 = (float)b0[head * HDIM + 64 + i] + (float)b1[head * HDIM + 64 + i];
            size_t o = ((size_t)(b * 32 + head) * S_LEN + s) * HDIM + i;
            Qb[o]      = (__bf16)((x1 * c - x2 * sn) * ATT_SCALE);
            Qb[o + 64] = (__bf16)((x2 * c + x1 * sn) * ATT_SCALE);
        } else {
            int g = head - 32;
            float x1 = (float)b0[QSZ + g * HDIM + i]      + (float)b1[QSZ + g * HDIM + i];
            float x2 = (float)b0[QSZ + g * HDIM + 64 + i] + (float)b1[QSZ + g * HDIM + 64 + i];
            size_t o = ((size_t)(b * 8 + g) * S_LEN + s) * HDIM + i;
            Kb[o]      = (__bf16)(x1 * c - x2 * sn);
            Kb[o + 64] = (__bf16)(x2 * c + x1 * sn);
        }
    }
}

// ---------------- V transpose: (P0+P1) V-slice -> Vt [B,8,128,S] bf16 ----------------
__global__ __launch_bounds__(256) void vtrans_kernel(const __bf16* __restrict__ qkv0,
                                                     const __bf16* __restrict__ qkv1,
                                                     __bf16* __restrict__ Vt) {
    __shared__ __bf16 T[64][132];
    const int tid = threadIdx.x;
    const int st = blockIdx.x, g = blockIdx.y, b = blockIdx.z;
    const size_t off = ((size_t)(b * S_LEN + st * 64)) * QKVSZ + (QSZ + KVSZ) + g * HDIM;
    const __bf16* s0 = qkv0 + off;
    const __bf16* s1 = qkv1 + off;
#pragma unroll
    for (int it = 0; it < 8; ++it) {
        int c = it * 256 + tid;       // 0..2047, 32 4-elem chunks per row
        int row = c >> 5;
        int c4 = c & 31;
        bf16x4 v0 = *(const bf16x4*)(s0 + (size_t)row * QKVSZ + c4 * 4);
        bf16x4 v1 = *(const bf16x4*)(s1 + (size_t)row * QKVSZ + c4 * 4);
        bf16x4 o;
#pragma unroll
        for (int k = 0; k < 4; ++k) o[k] = (__bf16)((float)v0[k] + (float)v1[k]);
        *(bf16x4*)(&T[row][c4 * 4]) = o;
    }
    __syncthreads();
#pragma unroll
    for (int it = 0; it < 8; ++it) {
        int c = it * 256 + tid;       // 0..2047, 16 chunks (of 4 s-cols) per d-row
        int d = c >> 4;
        int s4 = (c & 15) * 4;
        bf16x4 o;
        o[0] = T[s4 + 0][d]; o[1] = T[s4 + 1][d]; o[2] = T[s4 + 2][d]; o[3] = T[s4 + 3][d];
        *(bf16x4*)(Vt + ((size_t)(b * 8 + g) * HDIM + d) * S_LEN + st * 64 + s4) = o;
    }
}

// ---------------- Flash attention (causal, GQA rep=4) ----------------
// Paired q-tiles (qt=p and 7-p, constant 36 units/block; grid 256 = one
// balanced round). QBLK=256 (8 waves x 32 q-rows), KVBLK=64. Quad-buffered
// K/V (128KB LDS), depth-3 counted vmcnt + raw barrier pairs. Swapped QK^T +
// swapped PV, in-register P transpose via permlane swaps.
__global__ __launch_bounds__(512, 2) void attn_kernel(const __bf16* __restrict__ Q,
                                                      const __bf16* __restrict__ K,
                                                      const __bf16* __restrict__ Vt,
                                                      __bf16* __restrict__ O) {
    const int tid = threadIdx.x;
    const int w = tid >> 6, l = tid & 63;
    const int l15 = l & 15, l4 = l >> 4;
    const int flat = blockIdx.x + (blockIdx.y << 2) + (blockIdx.z << 7);  // 0..255
    const int swz = (flat & 7) * 32 + (flat >> 3);
    const int p = swz & 3;
    const int hb = swz >> 2;
    const int h = hb & 31, b = hb >> 5;
    const int g = h >> 2;

    __shared__ __bf16 Ks[4][64 * 128];   // 4x16 KB; chunk c: row=c>>4, cc=(c&15)^(row&7)
    __shared__ __bf16 Vs[4][128 * 64];   // 4x16 KB; chunk c: row=c>>3, cc=(c&7)^(row&7)

    const __bf16* Kp = K + (size_t)(b * 8 + g) * S_LEN * HDIM;
    const __bf16* Vp = Vt + (size_t)(b * 8 + g) * HDIM * S_LEN;

#define RED16(x, OPINS) do {                                                      \
        u32 ra_ = __builtin_bit_cast(u32, x), rb_;                                \
        asm("v_mov_b32 %0, %1" : "=v"(rb_) : "v"(ra_));                           \
        asm("v_permlane16_swap_b32 %0, %1" : "+v"(ra_), "+v"(rb_));               \
        x = OPINS(__builtin_bit_cast(float, ra_), __builtin_bit_cast(float, rb_));\
    } while (0)
#define RED32(x, OPINS) do {                                                      \
        u32 ra_ = __builtin_bit_cast(u32, x), rb_;                                \
        asm("v_mov_b32 %0, %1" : "=v"(rb_) : "v"(ra_));                           \
        asm("v_permlane32_swap_b32 %0, %1" : "+v"(ra_), "+v"(rb_));               \
        x = OPINS(__builtin_bit_cast(float, ra_), __builtin_bit_cast(float, rb_));\
    } while (0)
#define FADD_(a_, b_) ((a_) + (b_))

#define STAGE(ktile) do {                                                          \
        const int buf_ = (ktile) & 3;                                              \
        const __bf16* kbase = Kp + (size_t)(ktile) * 64 * HDIM;                    \
        _Pragma("unroll")                                                          \
        for (int i_ = 0; i_ < 2; ++i_) {                                           \
            int c_ = i_ * 512 + tid;            /* 1024 chunks = 64x128 bf16 */    \
            int row_ = c_ >> 4, cc_ = (c_ & 15) ^ (row_ & 7);                      \
            GLDS16(kbase + (size_t)row_ * HDIM + cc_ * 8,                          \
                   (char*)Ks[buf_] + c_ * 16);                                     \
        }                                                                          \
        const __bf16* vbase = Vp + (size_t)(ktile) * 64;                           \
        _Pragma("unroll")                                                          \
        for (int i_ = 0; i_ < 2; ++i_) {                                           \
            int c_ = i_ * 512 + tid;            /* 1024 chunks = 128x64 bf16 */    \
            int row_ = c_ >> 3, cc_ = (c_ & 7) ^ (row_ & 7);                       \
            GLDS16(vbase + (size_t)row_ * S_LEN + cc_ * 8,                         \
                   (char*)Vs[buf_] + c_ * 16);                                     \
        }                                                                          \
    } while (0)

    for (int pi = 0; pi < 2; ++pi) {
        const int qt = pi ? (7 - p) : p;
        const int qw0 = qt * 256 + w * 32;       // wave's first q-row
        const __bf16* Qp = Q + ((size_t)((b * 32 + h) * S_LEN + qw0)) * HDIM;

        bf16x8 qf[2][4];
#pragma unroll
        for (int qh = 0; qh < 2; ++qh)
#pragma unroll
            for (int kk = 0; kk < 4; ++kk)
                qf[qh][kk] = *(const bf16x8*)(Qp + (size_t)(qh * 16 + l15) * HDIM + kk * 32 + l4 * 8);

        f32x4 acc[2][8] = {};   // [qh][n]: D[d = n*16 + l4*4 + r][q = qw0+qh*16+l15]
        float m[2]    = {-1e30f, -1e30f};
        float lsum[2] = {0.f, 0.f};

        const int nkt = 4 * qt + 4;
        // pass-2 entry: retire pass-1 epilogue stores so counted vmcnt stays exact
        if (pi) { asm volatile("s_waitcnt vmcnt(0)" ::: "memory"); }
        STAGE(0);
        STAGE(1);
        STAGE(2);

        for (int kt = 0; kt < nkt; ++kt) {
            if (kt + 3 < nkt) STAGE(kt + 3);
            {
                int rem = nkt - 1 - kt;
                if (rem >= 3)      { asm volatile("s_waitcnt vmcnt(12)" ::: "memory"); }
                else if (rem == 2) { asm volatile("s_waitcnt vmcnt(8)"  ::: "memory"); }
                else if (rem == 1) { asm volatile("s_waitcnt vmcnt(4)"  ::: "memory"); }
                else               { asm volatile("s_waitcnt vmcnt(0)"  ::: "memory"); }
            }
            __builtin_amdgcn_sched_barrier(0);
            __builtin_amdgcn_s_barrier();      // barrier#1: tile kt visible to all
            __builtin_amdgcn_sched_barrier(0);
            const int cur = kt & 3;
            if (kt * 64 <= qw0 + 31) {         // wave-level causal skip
                f32x4 sfr[2][4];
                __builtin_amdgcn_s_setprio(1);
#pragma unroll
                for (int fn = 0; fn < 4; ++fn) {
                    f32x4 sa0 = {}, sa1 = {};
#pragma unroll
                    for (int kk = 0; kk < 4; ++kk) {
                        int row = fn * 16 + l15;
                        int cc = (kk * 4 + l4) ^ (l15 & 7);
                        bf16x8 kb = *(const bf16x8*)(Ks[cur] + row * HDIM + cc * 8);
                        sa0 = __builtin_amdgcn_mfma_f32_16x16x32_bf16(kb, qf[0][kk], sa0, 0, 0, 0);
                        sa1 = __builtin_amdgcn_mfma_f32_16x16x32_bf16(kb, qf[1][kk], sa1, 0, 0, 0);
                    }
                    sfr[0][fn] = sa0; sfr[1][fn] = sa1;
                }
                __builtin_amdgcn_s_setprio(0);
                const bool needmask = (kt * 64 + 63 > qw0);
                bf16x8 pb[2][2];
#pragma unroll
                for (int qh = 0; qh < 2; ++qh) {
                    const int qrow = qw0 + qh * 16 + l15;
                    float pmax = -1e30f;
#pragma unroll
                    for (int fn = 0; fn < 4; ++fn)
#pragma unroll
                        for (int r = 0; r < 4; ++r) {
                            float v = sfr[qh][fn][r];
                            if (needmask) {
                                int kcol = kt * 64 + fn * 16 + l4 * 4 + r;
                                if (kcol > qrow) v = -1e30f;
                            }
                            sfr[qh][fn][r] = v;
                            pmax = fmaxf(pmax, v);
                        }
                    RED16(pmax, fmaxf);
                    RED32(pmax, fmaxf);
                    if (!__all(pmax - m[qh] <= 8.0f)) {          // defer-max (rare)
                        float mn = fmaxf(m[qh], pmax);
                        float alpha = exp2f((m[qh] - mn) * L2E);
                        m[qh] = mn;
                        lsum[qh] *= alpha;
#pragma unroll
                        for (int n = 0; n < 8; ++n)
#pragma unroll
                            for (int r = 0; r < 4; ++r) acc[qh][n][r] *= alpha;
                    }
                    float rs = 0.f;
                    u32 pk01[4], pk23[4];
#pragma unroll
                    for (int fn = 0; fn < 4; ++fn) {
                        float p0 = exp2f((sfr[qh][fn][0] - m[qh]) * L2E);
                        float p1 = exp2f((sfr[qh][fn][1] - m[qh]) * L2E);
                        float p2 = exp2f((sfr[qh][fn][2] - m[qh]) * L2E);
                        float p3 = exp2f((sfr[qh][fn][3] - m[qh]) * L2E);
                        rs += (p0 + p1) + (p2 + p3);
                        asm("v_cvt_pk_bf16_f32 %0, %1, %2" : "=v"(pk01[fn]) : "v"(p0), "v"(p1));
                        asm("v_cvt_pk_bf16_f32 %0, %1, %2" : "=v"(pk23[fn]) : "v"(p2), "v"(p3));
                    }
                    RED16(rs, FADD_);
                    RED32(rs, FADD_);
                    lsum[qh] += rs;
#pragma unroll
                    for (int kk = 0; kk < 2; ++kk) {
                        u32 w0 = pk01[2 * kk], w2 = pk01[2 * kk + 1];
                        asm("v_permlane32_swap_b32 %0, %1" : "+v"(w0), "+v"(w2));
                        asm("v_permlane16_swap_b32 %0, %1" : "+v"(w0), "+v"(w2));
                        u32 w1 = pk23[2 * kk], w3 = pk23[2 * kk + 1];
                        asm("v_permlane32_swap_b32 %0, %1" : "+v"(w1), "+v"(w3));
                        asm("v_permlane16_swap_b32 %0, %1" : "+v"(w1), "+v"(w3));
                        u32x4 wv;
                        wv[0] = w0; wv[1] = w1; wv[2] = w2; wv[3] = w3;
                        pb[qh][kk] = __builtin_bit_cast(bf16x8, wv);
                    }
                }
                __builtin_amdgcn_s_setprio(1);
#pragma unroll
                for (int kk = 0; kk < 2; ++kk) {
#pragma unroll
                    for (int n = 0; n < 8; ++n) {
                        int row = n * 16 + l15;
                        int cc = (kk * 4 + l4) ^ (l15 & 7);
                        bf16x8 vb = *(const bf16x8*)(Vs[cur] + row * 64 + cc * 8);
                        acc[0][n] = __builtin_amdgcn_mfma_f32_16x16x32_bf16(vb, pb[0][kk], acc[0][n], 0, 0, 0);
                        acc[1][n] = __builtin_amdgcn_mfma_f32_16x16x32_bf16(vb, pb[1][kk], acc[1][n], 0, 0, 0);
                    }
                }
                __builtin_amdgcn_s_setprio(0);
            }
            __builtin_amdgcn_sched_barrier(0);
            __builtin_amdgcn_s_barrier();      // barrier#2: reads of slot kt done
            __builtin_amdgcn_sched_barrier(0);
        }
        // ---- epilogue: attn[b, q, h*128 + d], d = n*16 + l4*4 + r ----
#pragma unroll
        for (int qh = 0; qh < 2; ++qh) {
            float inv = 1.0f / lsum[qh];
            int qrow = qw0 + qh * 16 + l15;
            __bf16* obase = O + ((size_t)(b * S_LEN) + qrow) * QSZ + h * HDIM + l4 * 4;
#pragma unroll
            for (int n = 0; n < 8; ++n) {
                bf16x4 o4;
#pragma unroll
                for (int r = 0; r < 4; ++r) o4[r] = (__bf16)(acc[qh][n][r] * inv);
                *(bf16x4*)(obase + n * 16) = o4;
            }
        }
    }
#undef STAGE
#undef RED16
#undef RED32
#undef FADD_
}

extern "C" void kernel_launch(void* const* d_in, const int* in_sizes, int n_in,
                              void* d_out, int out_size, void* d_ws, size_t ws_size,
                              hipStream_t stream) {
    const int*   pos    = (const int*)d_in[0];
    const float* hidden = (const float*)d_in[1];
    const float* wqkv   = (const float*)d_in[2];
    const float* wo     = (const float*)d_in[3];
    float* out = (float*)d_out;

    // workspace carve (303 MB total, same as proven R0 footprint)
    __bf16* hb    = (__bf16*)d_ws;                     // 16,777,216 elems
    __bf16* wqb   = hb  + 16777216;                    // 25,165,824
    __bf16* wob   = wqb + 25165824;                    // 16,777,216
    __bf16* qkvP  = wob + 16777216;                    // 2 x 25,165,824 bf16 (split-K partials)
    __bf16* Qb    = qkvP + 2 * 25165824;               // 16,777,216
    __bf16* Kb    = Qb  + 16777216;                    // 4,194,304
    __bf16* Vtb   = Kb  + 4194304;                     // 4,194,304
    __bf16* attnb = Vtb + 4194304;                     // 16,777,216
    float*  rc    = (float*)(attnb + 16777216);        // 131,072
    float*  rs    = rc + 131072;                       // 131,072

    conv3_f32_bf16<<<2048, 256, 0, stream>>>(hidden, hb, 4194304,
                                             wqkv, wqb, 6291456,
                                             wo, wob, 4194304);
    rope_table_kernel<<<512, 256, 0, stream>>>(rc, rs);
    // QKV: split-K=2 -> 768 blocks = 3 exact rounds of 256 CUs
    gemm256<__bf16><<<dim3(QKVSZ / 256, (B_DIM * S_LEN) / 256, 2), 512, 0, stream>>>(
        hb, wqb, qkvP, QKVSZ, 32, (size_t)25165824);
    rope_kernel<<<B_DIM * S_LEN, 256, 0, stream>>>(qkvP, qkvP + 25165824, pos, rc, rs, Qb, Kb);
    vtrans_kernel<<<dim3(S_LEN / 64, NKV, B_DIM), 256, 0, stream>>>(qkvP, qkvP + 25165824, Vtb);
    attn_kernel<<<dim3(4, NHEADS, B_DIM), 512, 0, stream>>>(Qb, Kb, Vtb, attnb);
    // O-proj: 256 blocks exact, full K
    gemm256<float><<<dim3(HIDDEN / 256, (B_DIM * S_LEN) / 256, 1), 512, 0, stream>>>(
        attnb, wob, out, HIDDEN, 64, (size_t)0);
}

// Round 17
// 525.102 us; speedup vs baseline: 1.0105x; 1.0105x over previous
//
#include <hip/hip_runtime.h>
#include <hip/hip_bf16.h>
#include <cmath>

typedef __bf16 bf16x8 __attribute__((ext_vector_type(8)));
typedef __bf16 bf16x4 __attribute__((ext_vector_type(4)));
typedef float  f32x4  __attribute__((ext_vector_type(4)));
typedef unsigned int u32;
typedef u32 u32x4 __attribute__((ext_vector_type(4)));

#define AS1 __attribute__((address_space(1)))
#define AS3 __attribute__((address_space(3)))
#define GLDS16(gp, lp) __builtin_amdgcn_global_load_lds((AS1 void*)(gp), (AS3 void*)(lp), 16, 0, 0)

#define B_DIM 2
#define S_LEN 2048
#define HIDDEN 4096
#define NHEADS 32
#define NKV 8
#define HDIM 128
#define QSZ 4096
#define KVSZ 1024
#define QKVSZ 6144
#define GK 4096                /* K of both GEMMs */
#define ATT_SCALE 0.0078125f   /* 1/128, folded into Qb at RoPE time */
#define L2E 1.4426950408889634f

// ---------------- merged f32 -> bf16 conversion (3 buffers, grid-stride) ----------------
__global__ __launch_bounds__(256) void conv3_f32_bf16(const float* __restrict__ i0, __bf16* __restrict__ o0, int n0,
                                                      const float* __restrict__ i1, __bf16* __restrict__ o1, int n1,
                                                      const float* __restrict__ i2, __bf16* __restrict__ o2, int n2) {
    const int total = n0 + n1 + n2;
    for (int idx = blockIdx.x * 256 + threadIdx.x; idx < total; idx += gridDim.x * 256) {
        const float* in; __bf16* out; int j = idx;
        if (j < n0) { in = i0; out = o0; }
        else if ((j -= n0) < n1) { in = i1; out = o1; }
        else { j -= n1; in = i2; out = o2; }
        float4 v = ((const float4*)in)[j];
        bf16x4 o;
        o[0] = (__bf16)v.x; o[1] = (__bf16)v.y; o[2] = (__bf16)v.z; o[3] = (__bf16)v.w;
        ((bf16x4*)out)[j] = o;
    }
}

// ---------------- RoPE cos/sin table: [pos][i], i<64 ----------------
__global__ __launch_bounds__(256) void rope_table_kernel(float* __restrict__ ct,
                                                         float* __restrict__ st) {
    int idx = blockIdx.x * 256 + threadIdx.x;   // S_LEN*64 entries
    int p = idx >> 6, i = idx & 63;
    float inv = expf(-(float)i * (9.210340371976184f / 64.0f));
    float freq = (float)p * inv;
    float s, c;
    sincosf(freq, &s, &c);
    ct[idx] = c; st[idx] = s;
}

// ---------------- 256x256 4-phase/K-tile GEMM (R15 schedule) ----------------
// VDIR: blocks with n0 >= 5120 (the V-slice; tile-aligned) write transposed
// directly into Vt [B,8,128,S] (lane's r=0..3 = 4 consecutive s at fixed d).
template<typename OUT, bool VDIR>
__global__ __launch_bounds__(512, 2) void gemm256(const __bf16* __restrict__ A,
                                                  const __bf16* __restrict__ B,
                                                  OUT* __restrict__ C,
                                                  __bf16* __restrict__ Vt,
                                                  int N) {
    __shared__ __bf16 Asm[2 * 16384 + 2 * 16384];   // A: 2 slots x 32KB, B: 2 slots x 32KB
    char* Bbase = (char*)Asm + 65536;

    const int tid = threadIdx.x;
    const int w = tid >> 6, l = tid & 63;
    const int l15 = l & 15, l4 = l >> 4;
    const int wr = w >> 2, wc = w & 3;

    const int nwg = gridDim.x * gridDim.y;
    const int orig = blockIdx.y * gridDim.x + blockIdx.x;
    const int swz = (orig & 7) * (nwg >> 3) + (orig >> 3);
    const int bx = swz % gridDim.x, by = swz / gridDim.x;
    const int m0 = by * 256, n0 = bx * 256;

    const __bf16* Ag = A + (size_t)m0 * GK;
    const __bf16* Bg = B + (size_t)n0 * GK;

#define STAGE_AQ(q, tile) do {                                                  \
        int c_ = (q) * 512 + tid;                                               \
        int r_ = c_ >> 3;                                                       \
        int jg_ = (tid & 7) ^ (r_ & 7);                                         \
        GLDS16(Ag + (size_t)r_ * GK + (tile) * 64 + jg_ * 8,                    \
               (char*)Asm + ((tile) & 1) * 32768 + c_ * 16);                    \
    } while (0)
#define STAGE_BS(s, tile) do {                                                  \
        _Pragma("unroll")                                                       \
        for (int i_ = 0; i_ < 2; ++i_) {                                        \
            int v_ = i_ * 512 + tid;                                            \
            int r_ = (v_ >> 8) * 64 + (s) * 32 + ((v_ >> 3) & 31);              \
            int jg_ = (v_ & 7) ^ (r_ & 7);                                      \
            int c_ = r_ * 8 + (v_ & 7);                                         \
            GLDS16(Bg + (size_t)r_ * GK + (tile) * 64 + jg_ * 8,                \
                   Bbase + ((tile) & 1) * 32768 + c_ * 16);                     \
        }                                                                       \
    } while (0)

#define LOAD_A(DST, MH) do {                                                    \
        _Pragma("unroll")                                                       \
        for (int m2 = 0; m2 < 4; ++m2) {                                        \
            int row = wr * 128 + ((MH) * 4 + m2) * 16 + l15;                    \
            _Pragma("unroll")                                                   \
            for (int kk = 0; kk < 2; ++kk) {                                    \
                int j = (kk * 4 + l4) ^ (row & 7);                              \
                DST[m2][kk] = *(const bf16x8*)(Als + row * 64 + j * 8);         \
            }                                                                   \
        }                                                                       \
    } while (0)
#define LOAD_B(DST, NH) do {                                                    \
        _Pragma("unroll")                                                       \
        for (int n2 = 0; n2 < 2; ++n2) {                                        \
            int row = wc * 64 + ((NH) * 2 + n2) * 16 + l15;                     \
            _Pragma("unroll")                                                   \
            for (int kk = 0; kk < 2; ++kk) {                                    \
                int j = (kk * 4 + l4) ^ (row & 7);                              \
                DST[n2][kk] = *(const bf16x8*)(Bls + row * 64 + j * 8);         \
            }                                                                   \
        }                                                                       \
    } while (0)
#define MFMA_QUAD(AF, BF, MI0, NI0)                                             \
    _Pragma("unroll")                                                           \
    for (int m2 = 0; m2 < 4; ++m2)                                              \
        _Pragma("unroll")                                                       \
        for (int n2 = 0; n2 < 2; ++n2)                                          \
            _Pragma("unroll")                                                   \
            for (int kk = 0; kk < 2; ++kk)                                      \
                acc[(MI0) + m2][(NI0) + n2] =                                   \
                    __builtin_amdgcn_mfma_f32_16x16x32_bf16(                    \
                        AF[m2][kk], BF[n2][kk], acc[(MI0) + m2][(NI0) + n2], 0, 0, 0);

    f32x4 acc[8][4] = {};

    const int T = GK / 64;   // 64 K-tiles
    STAGE_AQ(0, 0); STAGE_AQ(1, 0); STAGE_AQ(2, 0); STAGE_AQ(3, 0);
    STAGE_BS(0, 0); STAGE_BS(1, 0);
    STAGE_AQ(0, 1); STAGE_AQ(2, 1); STAGE_BS(0, 1);
    asm volatile("s_waitcnt vmcnt(4)" ::: "memory");
    __builtin_amdgcn_s_barrier();

    for (int t = 0; t < T; ++t) {
        const __bf16* Als = Asm + (t & 1) * 16384;
        const __bf16* Bls = (__bf16*)Bbase + (t & 1) * 16384;
        bf16x8 af0[4][2], af1[4][2], bfr[2][2];
        // ---- ph0: MH0 x NH0 ---- (af0 loaded once, lives through ph1)
        LOAD_A(af0, 0);
        LOAD_B(bfr, 0);
        if (t + 1 < T) { STAGE_AQ(1, t + 1); STAGE_AQ(3, t + 1); }
        __builtin_amdgcn_s_barrier();
        __builtin_amdgcn_s_setprio(1);
        MFMA_QUAD(af0, bfr, 0, 0);
        __builtin_amdgcn_s_setprio(0);
        __builtin_amdgcn_s_barrier();
        // ---- ph1: MH0 x NH1 ---- (reuse af0)
        LOAD_B(bfr, 1);
        if (t + 1 < T) STAGE_BS(1, t + 1);
        __builtin_amdgcn_s_barrier();
        __builtin_amdgcn_s_setprio(1);
        MFMA_QUAD(af0, bfr, 0, 2);
        __builtin_amdgcn_s_setprio(0);
        __builtin_amdgcn_s_barrier();
        // ---- ph2: MH1 x NH0 ---- (af1 loaded once, lives through ph3)
        LOAD_A(af1, 1);
        LOAD_B(bfr, 0);
        if (t + 2 < T) { STAGE_AQ(0, t + 2); STAGE_AQ(2, t + 2); }
        __builtin_amdgcn_s_barrier();
        __builtin_amdgcn_s_setprio(1);
        MFMA_QUAD(af1, bfr, 4, 0);
        __builtin_amdgcn_s_setprio(0);
        __builtin_amdgcn_s_barrier();
        // ---- ph3: MH1 x NH1 ---- (reuse af1)
        LOAD_B(bfr, 1);
        if (t + 2 < T) STAGE_BS(0, t + 2);
        __builtin_amdgcn_s_barrier();
        __builtin_amdgcn_s_setprio(1);
        MFMA_QUAD(af1, bfr, 4, 2);
        __builtin_amdgcn_s_setprio(0);
        if (t + 2 < T)      { asm volatile("s_waitcnt vmcnt(4)" ::: "memory"); }
        else if (t + 1 < T) { asm volatile("s_waitcnt vmcnt(0)" ::: "memory"); }
        __builtin_amdgcn_s_barrier();
    }
#undef MFMA_QUAD
#undef LOAD_A
#undef LOAD_B
#undef STAGE_AQ
#undef STAGE_BS

    if (VDIR && n0 >= QSZ + KVSZ) {
        // V-slice block: write transposed into Vt [B*8, 128, S_LEN]
#pragma unroll
        for (int mi = 0; mi < 8; ++mi) {
            int s0 = m0 + wr * 128 + mi * 16 + l4 * 4;   // 4 consecutive tokens
            int b = s0 >> 11, s = s0 & 2047;
#pragma unroll
            for (int ni = 0; ni < 4; ++ni) {
                int vcol = n0 - (QSZ + KVSZ) + wc * 64 + ni * 16 + l15;
                int g = vcol >> 7, d = vcol & 127;
                bf16x4 o4;
#pragma unroll
                for (int r = 0; r < 4; ++r) o4[r] = (__bf16)acc[mi][ni][r];
                *(bf16x4*)(Vt + ((size_t)((b * 8 + g) * HDIM + d)) * S_LEN + s) = o4;
            }
        }
    } else {
#pragma unroll
        for (int mi = 0; mi < 8; ++mi)
#pragma unroll
            for (int ni = 0; ni < 4; ++ni)
#pragma unroll
                for (int r = 0; r < 4; ++r)
                    C[(size_t)(m0 + wr * 128 + mi * 16 + l4 * 4 + r) * N
                      + n0 + wc * 64 + ni * 16 + l15] = (OUT)acc[mi][ni][r];
    }
}

// ---------------- RoPE apply: qkv bf16 -> Q (pre-scaled) [B,32,S,128], K [B,8,S,128] bf16 ----------------
__global__ __launch_bounds__(256) void rope_kernel(const __bf16* __restrict__ qkv,
                                                   const int* __restrict__ pos,
                                                   const float* __restrict__ ct,
                                                   const float* __restrict__ st,
                                                   __bf16* __restrict__ Qb,
                                                   __bf16* __restrict__ Kb) {
    const int tid = threadIdx.x;
    const int tok = blockIdx.x;                 // 0..B*S-1
    const int b = tok >> 11, s = tok & 2047;
    const int p = pos[tok];
    const __bf16* base = qkv + (size_t)tok * QKVSZ;
    const float* cb = ct + (size_t)p * 64;
    const float* sb = st + (size_t)p * 64;
    for (int idx = tid; idx < 2560; idx += 256) {   // (32+8)*64 pairs
        int head = idx >> 6, i = idx & 63;
        float c = cb[i], sn = sb[i];
        if (head < 32) {
            float x1 = (float)base[head * HDIM + i];
            float x2 = (float)base[head * HDIM + 64 + i];
            size_t o = ((size_t)(b * 32 + head) * S_LEN + s) * HDIM + i;
            Qb[o]      = (__bf16)((x1 * c - x2 * sn) * ATT_SCALE);
            Qb[o + 64] = (__bf16)((x2 * c + x1 * sn) * ATT_SCALE);
        } else {
            int g = head - 32;
            float x1 = (float)base[QSZ + g * HDIM + i];
            float x2 = (float)base[QSZ + g * HDIM + 64 + i];
            size_t o = ((size_t)(b * 8 + g) * S_LEN + s) * HDIM + i;
            Kb[o]      = (__bf16)(x1 * c - x2 * sn);
            Kb[o + 64] = (__bf16)(x2 * c + x1 * sn);
        }
    }
}

// ---------------- Flash attention (causal, GQA rep=4) ----------------
// Paired q-tiles (qt=p and 7-p, constant 36 units/block; grid 256 = one
// balanced round). QBLK=256 (8 waves x 32 q-rows), KVBLK=64. Quad-buffered
// K/V (128KB LDS), depth-3 counted vmcnt + raw barrier pairs. Swapped QK^T +
// swapped PV, in-register P transpose via permlane swaps.
__global__ __launch_bounds__(512, 2) void attn_kernel(const __bf16* __restrict__ Q,
                                                      const __bf16* __restrict__ K,
                                                      const __bf16* __restrict__ Vt,
                                                      __bf16* __restrict__ O) {
    const int tid = threadIdx.x;
    const int w = tid >> 6, l = tid & 63;
    const int l15 = l & 15, l4 = l >> 4;
    const int flat = blockIdx.x + (blockIdx.y << 2) + (blockIdx.z << 7);  // 0..255
    const int swz = (flat & 7) * 32 + (flat >> 3);
    const int p = swz & 3;
    const int hb = swz >> 2;
    const int h = hb & 31, b = hb >> 5;
    const int g = h >> 2;

    __shared__ __bf16 Ks[4][64 * 128];   // 4x16 KB; chunk c: row=c>>4, cc=(c&15)^(row&7)
    __shared__ __bf16 Vs[4][128 * 64];   // 4x16 KB; chunk c: row=c>>3, cc=(c&7)^(row&7)

    const __bf16* Kp = K + (size_t)(b * 8 + g) * S_LEN * HDIM;
    const __bf16* Vp = Vt + (size_t)(b * 8 + g) * HDIM * S_LEN;

#define RED16(x, OPINS) do {                                                      \
        u32 ra_ = __builtin_bit_cast(u32, x), rb_;                                \
        asm("v_mov_b32 %0, %1" : "=v"(rb_) : "v"(ra_));                           \
        asm("v_permlane16_swap_b32 %0, %1" : "+v"(ra_), "+v"(rb_));               \
        x = OPINS(__builtin_bit_cast(float, ra_), __builtin_bit_cast(float, rb_));\
    } while (0)
#define RED32(x, OPINS) do {                                                      \
        u32 ra_ = __builtin_bit_cast(u32, x), rb_;                                \
        asm("v_mov_b32 %0, %1" : "=v"(rb_) : "v"(ra_));                           \
        asm("v_permlane32_swap_b32 %0, %1" : "+v"(ra_), "+v"(rb_));               \
        x = OPINS(__builtin_bit_cast(float, ra_), __builtin_bit_cast(float, rb_));\
    } while (0)
#define FADD_(a_, b_) ((a_) + (b_))

#define STAGE(ktile) do {                                                          \
        const int buf_ = (ktile) & 3;                                              \
        const __bf16* kbase = Kp + (size_t)(ktile) * 64 * HDIM;                    \
        _Pragma("unroll")                                                          \
        for (int i_ = 0; i_ < 2; ++i_) {                                           \
            int c_ = i_ * 512 + tid;            /* 1024 chunks = 64x128 bf16 */    \
            int row_ = c_ >> 4, cc_ = (c_ & 15) ^ (row_ & 7);                      \
            GLDS16(kbase + (size_t)row_ * HDIM + cc_ * 8,                          \
                   (char*)Ks[buf_] + c_ * 16);                                     \
        }                                                                          \
        const __bf16* vbase = Vp + (size_t)(ktile) * 64;                           \
        _Pragma("unroll")                                                          \
        for (int i_ = 0; i_ < 2; ++i_) {                                           \
            int c_ = i_ * 512 + tid;            /* 1024 chunks = 128x64 bf16 */    \
            int row_ = c_ >> 3, cc_ = (c_ & 7) ^ (row_ & 7);                       \
            GLDS16(vbase + (size_t)row_ * S_LEN + cc_ * 8,                         \
                   (char*)Vs[buf_] + c_ * 16);                                     \
        }                                                                          \
    } while (0)

    for (int pi = 0; pi < 2; ++pi) {
        const int qt = pi ? (7 - p) : p;
        const int qw0 = qt * 256 + w * 32;       // wave's first q-row
        const __bf16* Qp = Q + ((size_t)((b * 32 + h) * S_LEN + qw0)) * HDIM;

        bf16x8 qf[2][4];
#pragma unroll
        for (int qh = 0; qh < 2; ++qh)
#pragma unroll
            for (int kk = 0; kk < 4; ++kk)
                qf[qh][kk] = *(const bf16x8*)(Qp + (size_t)(qh * 16 + l15) * HDIM + kk * 32 + l4 * 8);

        f32x4 acc[2][8] = {};   // [qh][n]: D[d = n*16 + l4*4 + r][q = qw0+qh*16+l15]
        float m[2]    = {-1e30f, -1e30f};
        float lsum[2] = {0.f, 0.f};

        const int nkt = 4 * qt + 4;
        // pass-2 entry: retire pass-1 epilogue stores so counted vmcnt stays exact
        if (pi) { asm volatile("s_waitcnt vmcnt(0)" ::: "memory"); }
        STAGE(0);
        STAGE(1);
        STAGE(2);

        for (int kt = 0; kt < nkt; ++kt) {
            if (kt + 3 < nkt) STAGE(kt + 3);
            {
                int rem = nkt - 1 - kt;
                if (rem >= 3)      { asm volatile("s_waitcnt vmcnt(12)" ::: "memory"); }
                else if (rem == 2) { asm volatile("s_waitcnt vmcnt(8)"  ::: "memory"); }
                else if (rem == 1) { asm volatile("s_waitcnt vmcnt(4)"  ::: "memory"); }
                else               { asm volatile("s_waitcnt vmcnt(0)"  ::: "memory"); }
            }
            __builtin_amdgcn_sched_barrier(0);
            __builtin_amdgcn_s_barrier();      // barrier#1: tile kt visible to all
            __builtin_amdgcn_sched_barrier(0);
            const int cur = kt & 3;
            if (kt * 64 <= qw0 + 31) {         // wave-level causal skip
                f32x4 sfr[2][4];
                __builtin_amdgcn_s_setprio(1);
#pragma unroll
                for (int fn = 0; fn < 4; ++fn) {
                    f32x4 sa0 = {}, sa1 = {};
#pragma unroll
                    for (int kk = 0; kk < 4; ++kk) {
                        int row = fn * 16 + l15;
                        int cc = (kk * 4 + l4) ^ (l15 & 7);
                        bf16x8 kb = *(const bf16x8*)(Ks[cur] + row * HDIM + cc * 8);
                        sa0 = __builtin_amdgcn_mfma_f32_16x16x32_bf16(kb, qf[0][kk], sa0, 0, 0, 0);
                        sa1 = __builtin_amdgcn_mfma_f32_16x16x32_bf16(kb, qf[1][kk], sa1, 0, 0, 0);
                    }
                    sfr[0][fn] = sa0; sfr[1][fn] = sa1;
                }
                __builtin_amdgcn_s_setprio(0);
                const bool needmask = (kt * 64 + 63 > qw0);
                bf16x8 pb[2][2];
#pragma unroll
                for (int qh = 0; qh < 2; ++qh) {
                    const int qrow = qw0 + qh * 16 + l15;
                    float pmax = -1e30f;
#pragma unroll
                    for (int fn = 0; fn < 4; ++fn)
#pragma unroll
                        for (int r = 0; r < 4; ++r) {
                            float v = sfr[qh][fn][r];
                            if (needmask) {
                                int kcol = kt * 64 + fn * 16 + l4 * 4 + r;
                                if (kcol > qrow) v = -1e30f;
                            }
                            sfr[qh][fn][r] = v;
                            pmax = fmaxf(pmax, v);
                        }
                    RED16(pmax, fmaxf);
                    RED32(pmax, fmaxf);
                    if (!__all(pmax - m[qh] <= 8.0f)) {          // defer-max (rare)
                        float mn = fmaxf(m[qh], pmax);
                        float alpha = exp2f((m[qh] - mn) * L2E);
                        m[qh] = mn;
                        lsum[qh] *= alpha;
#pragma unroll
                        for (int n = 0; n < 8; ++n)
#pragma unroll
                            for (int r = 0; r < 4; ++r) acc[qh][n][r] *= alpha;
                    }
                    float rs = 0.f;
                    u32 pk01[4], pk23[4];
#pragma unroll
                    for (int fn = 0; fn < 4; ++fn) {
                        float p0 = exp2f((sfr[qh][fn][0] - m[qh]) * L2E);
                        float p1 = exp2f((sfr[qh][fn][1] - m[qh]) * L2E);
                        float p2 = exp2f((sfr[qh][fn][2] - m[qh]) * L2E);
                        float p3 = exp2f((sfr[qh][fn][3] - m[qh]) * L2E);
                        rs += (p0 + p1) + (p2 + p3);
                        asm("v_cvt_pk_bf16_f32 %0, %1, %2" : "=v"(pk01[fn]) : "v"(p0), "v"(p1));
                        asm("v_cvt_pk_bf16_f32 %0, %1, %2" : "=v"(pk23[fn]) : "v"(p2), "v"(p3));
                    }
                    RED16(rs, FADD_);
                    RED32(rs, FADD_);
                    lsum[qh] += rs;
#pragma unroll
                    for (int kk = 0; kk < 2; ++kk) {
                        u32 w0 = pk01[2 * kk], w2 = pk01[2 * kk + 1];
                        asm("v_permlane32_swap_b32 %0, %1" : "+v"(w0), "+v"(w2));
                        asm("v_permlane16_swap_b32 %0, %1" : "+v"(w0), "+v"(w2));
                        u32 w1 = pk23[2 * kk], w3 = pk23[2 * kk + 1];
                        asm("v_permlane32_swap_b32 %0, %1" : "+v"(w1), "+v"(w3));
                        asm("v_permlane16_swap_b32 %0, %1" : "+v"(w1), "+v"(w3));
                        u32x4 wv;
                        wv[0] = w0; wv[1] = w1; wv[2] = w2; wv[3] = w3;
                        pb[qh][kk] = __builtin_bit_cast(bf16x8, wv);
                    }
                }
                __builtin_amdgcn_s_setprio(1);
#pragma unroll
                for (int kk = 0; kk < 2; ++kk) {
#pragma unroll
                    for (int n = 0; n < 8; ++n) {
                        int row = n * 16 + l15;
                        int cc = (kk * 4 + l4) ^ (l15 & 7);
                        bf16x8 vb = *(const bf16x8*)(Vs[cur] + row * 64 + cc * 8);
                        acc[0][n] = __builtin_amdgcn_mfma_f32_16x16x32_bf16(vb, pb[0][kk], acc[0][n], 0, 0, 0);
                        acc[1][n] = __builtin_amdgcn_mfma_f32_16x16x32_bf16(vb, pb[1][kk], acc[1][n], 0, 0, 0);
                    }
                }
                __builtin_amdgcn_s_setprio(0);
            }
            __builtin_amdgcn_sched_barrier(0);
            __builtin_amdgcn_s_barrier();      // barrier#2: reads of slot kt done
            __builtin_amdgcn_sched_barrier(0);
        }
        // ---- epilogue: attn[b, q, h*128 + d], d = n*16 + l4*4 + r ----
#pragma unroll
        for (int qh = 0; qh < 2; ++qh) {
            float inv = 1.0f / lsum[qh];
            int qrow = qw0 + qh * 16 + l15;
            __bf16* obase = O + ((size_t)(b * S_LEN) + qrow) * QSZ + h * HDIM + l4 * 4;
#pragma unroll
            for (int n = 0; n < 8; ++n) {
                bf16x4 o4;
#pragma unroll
                for (int r = 0; r < 4; ++r) o4[r] = (__bf16)(acc[qh][n][r] * inv);
                *(bf16x4*)(obase + n * 16) = o4;
            }
        }
    }
#undef STAGE
#undef RED16
#undef RED32
#undef FADD_
}

extern "C" void kernel_launch(void* const* d_in, const int* in_sizes, int n_in,
                              void* d_out, int out_size, void* d_ws, size_t ws_size,
                              hipStream_t stream) {
    const int*   pos    = (const int*)d_in[0];
    const float* hidden = (const float*)d_in[1];
    const float* wqkv   = (const float*)d_in[2];
    const float* wo     = (const float*)d_in[3];
    float* out = (float*)d_out;

    // workspace carve
    __bf16* hb    = (__bf16*)d_ws;                     // 16,777,216 elems
    __bf16* wqb   = hb  + 16777216;                    // 25,165,824
    __bf16* wob   = wqb + 25165824;                    // 16,777,216
    __bf16* qkv   = wob + 16777216;                    // 25,165,824 bf16 (V slice unused)
    __bf16* Qb    = qkv + 25165824;                    // 16,777,216
    __bf16* Kb    = Qb  + 16777216;                    // 4,194,304
    __bf16* Vtb   = Kb  + 4194304;                     // 4,194,304
    __bf16* attnb = Vtb + 4194304;                     // 16,777,216
    float*  rc    = (float*)(attnb + 16777216);        // 131,072
    float*  rs    = rc + 131072;                       // 131,072

    conv3_f32_bf16<<<2048, 256, 0, stream>>>(hidden, hb, 4194304,
                                             wqkv, wqb, 6291456,
                                             wo, wob, 4194304);
    rope_table_kernel<<<512, 256, 0, stream>>>(rc, rs);
    // QKV GEMM: V-slice blocks (n0 >= 5120) write transposed直接 into Vtb
    gemm256<__bf16, true><<<dim3(QKVSZ / 256, (B_DIM * S_LEN) / 256), 512, 0, stream>>>(
        hb, wqb, qkv, Vtb, QKVSZ);
    rope_kernel<<<B_DIM * S_LEN, 256, 0, stream>>>(qkv, pos, rc, rs, Qb, Kb);
    attn_kernel<<<dim3(4, NHEADS, B_DIM), 512, 0, stream>>>(Qb, Kb, Vtb, attnb);
    gemm256<float, false><<<dim3(HIDDEN / 256, (B_DIM * S_LEN) / 256), 512, 0, stream>>>(
        attnb, wob, out, nullptr, HIDDEN);
}

// Round 18
// 514.959 us; speedup vs baseline: 1.0304x; 1.0197x over previous
//
#include <hip/hip_runtime.h>
#include <hip/hip_bf16.h>
#include <cmath>

typedef __bf16 bf16x8 __attribute__((ext_vector_type(8)));
typedef __bf16 bf16x4 __attribute__((ext_vector_type(4)));
typedef float  f32x4  __attribute__((ext_vector_type(4)));
typedef unsigned int u32;
typedef u32 u32x4 __attribute__((ext_vector_type(4)));

#define AS1 __attribute__((address_space(1)))
#define AS3 __attribute__((address_space(3)))
#define GLDS16(gp, lp) __builtin_amdgcn_global_load_lds((AS1 void*)(gp), (AS3 void*)(lp), 16, 0, 0)

#define B_DIM 2
#define S_LEN 2048
#define HIDDEN 4096
#define NHEADS 32
#define NKV 8
#define HDIM 128
#define QSZ 4096
#define KVSZ 1024
#define QKVSZ 6144
#define GK 4096                /* K of both GEMMs */
#define ATT_SCALE 0.0078125f   /* 1/128, folded into Qb at RoPE time */
#define L2E 1.4426950408889634f

// ---------------- merged f32 -> bf16 conversion (3 buffers, grid-stride) ----------------
__global__ __launch_bounds__(256) void conv3_f32_bf16(const float* __restrict__ i0, __bf16* __restrict__ o0, int n0,
                                                      const float* __restrict__ i1, __bf16* __restrict__ o1, int n1,
                                                      const float* __restrict__ i2, __bf16* __restrict__ o2, int n2) {
    const int total = n0 + n1 + n2;
    for (int idx = blockIdx.x * 256 + threadIdx.x; idx < total; idx += gridDim.x * 256) {
        const float* in; __bf16* out; int j = idx;
        if (j < n0) { in = i0; out = o0; }
        else if ((j -= n0) < n1) { in = i1; out = o1; }
        else { j -= n1; in = i2; out = o2; }
        float4 v = ((const float4*)in)[j];
        bf16x4 o;
        o[0] = (__bf16)v.x; o[1] = (__bf16)v.y; o[2] = (__bf16)v.z; o[3] = (__bf16)v.w;
        ((bf16x4*)out)[j] = o;
    }
}

// ---------------- RoPE cos/sin table: [pos][i], i<64 ----------------
__global__ __launch_bounds__(256) void rope_table_kernel(float* __restrict__ ct,
                                                         float* __restrict__ st) {
    int idx = blockIdx.x * 256 + threadIdx.x;   // S_LEN*64 entries
    int p = idx >> 6, i = idx & 63;
    float inv = expf(-(float)i * (9.210340371976184f / 64.0f));
    float freq = (float)p * inv;
    float s, c;
    sincosf(freq, &s, &c);
    ct[idx] = c; st[idx] = s;
}

// ---------------- 256x256 4-phase/K-tile GEMM (R15 schedule + full B-residency) ----------------
// B NH0/NH1 fragment sets held in registers across the MH pair: 24 ds_read_b128
// per wave per K-tile (was 32) -> LDS-read traffic -25%.
// VDIR: blocks with n0 >= 5120 (the V-slice) write transposed into Vt.
template<typename OUT, bool VDIR>
__global__ __launch_bounds__(512, 2) void gemm256(const __bf16* __restrict__ A,
                                                  const __bf16* __restrict__ B,
                                                  OUT* __restrict__ C,
                                                  __bf16* __restrict__ Vt,
                                                  int N) {
    __shared__ __bf16 Asm[2 * 16384 + 2 * 16384];   // A: 2 slots x 32KB, B: 2 slots x 32KB
    char* Bbase = (char*)Asm + 65536;

    const int tid = threadIdx.x;
    const int w = tid >> 6, l = tid & 63;
    const int l15 = l & 15, l4 = l >> 4;
    const int wr = w >> 2, wc = w & 3;

    const int nwg = gridDim.x * gridDim.y;
    const int orig = blockIdx.y * gridDim.x + blockIdx.x;
    const int swz = (orig & 7) * (nwg >> 3) + (orig >> 3);
    const int bx = swz % gridDim.x, by = swz / gridDim.x;
    const int m0 = by * 256, n0 = bx * 256;

    const __bf16* Ag = A + (size_t)m0 * GK;
    const __bf16* Bg = B + (size_t)n0 * GK;

#define STAGE_AQ(q, tile) do {                                                  \
        int c_ = (q) * 512 + tid;                                               \
        int r_ = c_ >> 3;                                                       \
        int jg_ = (tid & 7) ^ (r_ & 7);                                         \
        GLDS16(Ag + (size_t)r_ * GK + (tile) * 64 + jg_ * 8,                    \
               (char*)Asm + ((tile) & 1) * 32768 + c_ * 16);                    \
    } while (0)
#define STAGE_BS(s, tile) do {                                                  \
        _Pragma("unroll")                                                       \
        for (int i_ = 0; i_ < 2; ++i_) {                                        \
            int v_ = i_ * 512 + tid;                                            \
            int r_ = (v_ >> 8) * 64 + (s) * 32 + ((v_ >> 3) & 31);              \
            int jg_ = (v_ & 7) ^ (r_ & 7);                                      \
            int c_ = r_ * 8 + (v_ & 7);                                         \
            GLDS16(Bg + (size_t)r_ * GK + (tile) * 64 + jg_ * 8,                \
                   Bbase + ((tile) & 1) * 32768 + c_ * 16);                     \
        }                                                                       \
    } while (0)

#define LOAD_A(DST, MH) do {                                                    \
        _Pragma("unroll")                                                       \
        for (int m2 = 0; m2 < 4; ++m2) {                                        \
            int row = wr * 128 + ((MH) * 4 + m2) * 16 + l15;                    \
            _Pragma("unroll")                                                   \
            for (int kk = 0; kk < 2; ++kk) {                                    \
                int j = (kk * 4 + l4) ^ (row & 7);                              \
                DST[m2][kk] = *(const bf16x8*)(Als + row * 64 + j * 8);         \
            }                                                                   \
        }                                                                       \
    } while (0)
#define LOAD_B(DST, NH) do {                                                    \
        _Pragma("unroll")                                                       \
        for (int n2 = 0; n2 < 2; ++n2) {                                        \
            int row = wc * 64 + ((NH) * 2 + n2) * 16 + l15;                     \
            _Pragma("unroll")                                                   \
            for (int kk = 0; kk < 2; ++kk) {                                    \
                int j = (kk * 4 + l4) ^ (row & 7);                              \
                DST[n2][kk] = *(const bf16x8*)(Bls + row * 64 + j * 8);         \
            }                                                                   \
        }                                                                       \
    } while (0)
#define MFMA_QUAD(AF, BF, MI0, NI0)                                             \
    _Pragma("unroll")                                                           \
    for (int m2 = 0; m2 < 4; ++m2)                                              \
        _Pragma("unroll")                                                       \
        for (int n2 = 0; n2 < 2; ++n2)                                          \
            _Pragma("unroll")                                                   \
            for (int kk = 0; kk < 2; ++kk)                                      \
                acc[(MI0) + m2][(NI0) + n2] =                                   \
                    __builtin_amdgcn_mfma_f32_16x16x32_bf16(                    \
                        AF[m2][kk], BF[n2][kk], acc[(MI0) + m2][(NI0) + n2], 0, 0, 0);

    f32x4 acc[8][4] = {};

    const int T = GK / 64;   // 64 K-tiles
    STAGE_AQ(0, 0); STAGE_AQ(1, 0); STAGE_AQ(2, 0); STAGE_AQ(3, 0);
    STAGE_BS(0, 0); STAGE_BS(1, 0);
    STAGE_AQ(0, 1); STAGE_AQ(2, 1); STAGE_BS(0, 1);
    asm volatile("s_waitcnt vmcnt(4)" ::: "memory");
    __builtin_amdgcn_s_barrier();

    for (int t = 0; t < T; ++t) {
        const __bf16* Als = Asm + (t & 1) * 16384;
        const __bf16* Bls = (__bf16*)Bbase + (t & 1) * 16384;
        bf16x8 af0[4][2], af1[4][2], bA[2][2], bB[2][2];
        // ---- ph0: MH0 x NH0 ---- (af0 lives through ph1; bA through ph2)
        LOAD_A(af0, 0);
        LOAD_B(bA, 0);
        if (t + 1 < T) { STAGE_AQ(1, t + 1); STAGE_AQ(3, t + 1); }
        __builtin_amdgcn_s_barrier();
        __builtin_amdgcn_s_setprio(1);
        MFMA_QUAD(af0, bA, 0, 0);
        __builtin_amdgcn_s_setprio(0);
        __builtin_amdgcn_s_barrier();
        // ---- ph1: MH0 x NH1 ---- (bB lives through ph3)
        LOAD_B(bB, 1);
        if (t + 1 < T) STAGE_BS(1, t + 1);
        __builtin_amdgcn_s_barrier();
        __builtin_amdgcn_s_setprio(1);
        MFMA_QUAD(af0, bB, 0, 2);
        __builtin_amdgcn_s_setprio(0);
        __builtin_amdgcn_s_barrier();
        // ---- ph2: MH1 x NH0 ---- (reuse bA; no B reload)
        LOAD_A(af1, 1);
        if (t + 2 < T) { STAGE_AQ(0, t + 2); STAGE_AQ(2, t + 2); }
        __builtin_amdgcn_s_barrier();
        __builtin_amdgcn_s_setprio(1);
        MFMA_QUAD(af1, bA, 4, 0);
        __builtin_amdgcn_s_setprio(0);
        __builtin_amdgcn_s_barrier();
        // ---- ph3: MH1 x NH1 ---- (reuse bB; no ds_reads at all)
        if (t + 2 < T) STAGE_BS(0, t + 2);
        __builtin_amdgcn_s_barrier();
        __builtin_amdgcn_s_setprio(1);
        MFMA_QUAD(af1, bB, 4, 2);
        __builtin_amdgcn_s_setprio(0);
        if (t + 2 < T)      { asm volatile("s_waitcnt vmcnt(4)" ::: "memory"); }
        else if (t + 1 < T) { asm volatile("s_waitcnt vmcnt(0)" ::: "memory"); }
        __builtin_amdgcn_s_barrier();
    }
#undef MFMA_QUAD
#undef LOAD_A
#undef LOAD_B
#undef STAGE_AQ
#undef STAGE_BS

    if (VDIR && n0 >= QSZ + KVSZ) {
        // V-slice block: write transposed into Vt [B*8, 128, S_LEN]
#pragma unroll
        for (int mi = 0; mi < 8; ++mi) {
            int s0 = m0 + wr * 128 + mi * 16 + l4 * 4;   // 4 consecutive tokens
            int b = s0 >> 11, s = s0 & 2047;
#pragma unroll
            for (int ni = 0; ni < 4; ++ni) {
                int vcol = n0 - (QSZ + KVSZ) + wc * 64 + ni * 16 + l15;
                int g = vcol >> 7, d = vcol & 127;
                bf16x4 o4;
#pragma unroll
                for (int r = 0; r < 4; ++r) o4[r] = (__bf16)acc[mi][ni][r];
                *(bf16x4*)(Vt + ((size_t)((b * 8 + g) * HDIM + d)) * S_LEN + s) = o4;
            }
        }
    } else {
#pragma unroll
        for (int mi = 0; mi < 8; ++mi)
#pragma unroll
            for (int ni = 0; ni < 4; ++ni)
#pragma unroll
                for (int r = 0; r < 4; ++r)
                    C[(size_t)(m0 + wr * 128 + mi * 16 + l4 * 4 + r) * N
                      + n0 + wc * 64 + ni * 16 + l15] = (OUT)acc[mi][ni][r];
    }
}

// ---------------- RoPE apply (vectorized): qkv bf16 -> Q (pre-scaled), K bf16 ----------------
__global__ __launch_bounds__(256) void rope_kernel(const __bf16* __restrict__ qkv,
                                                   const int* __restrict__ pos,
                                                   const float* __restrict__ ct,
                                                   const float* __restrict__ st,
                                                   __bf16* __restrict__ Qb,
                                                   __bf16* __restrict__ Kb) {
    const int tid = threadIdx.x;
    const int tok = blockIdx.x;                 // 0..B*S-1
    const int b = tok >> 11, s = tok & 2047;
    const int p = pos[tok];
    const __bf16* base = qkv + (size_t)tok * QKVSZ;
    const float* cb = ct + (size_t)p * 64;
    const float* sb = st + (size_t)p * 64;
    for (int u = tid; u < 640; u += 256) {      // (32+8) heads x 16 quad-units
        int head = u >> 4, i = (u & 15) * 4;
        float4 c4 = *(const float4*)(cb + i);
        float4 s4 = *(const float4*)(sb + i);
        const bool isQ = (head < 32);
        const __bf16* src = base + (isQ ? head * HDIM : QSZ + (head - 32) * HDIM);
        bf16x4 x1 = *(const bf16x4*)(src + i);
        bf16x4 x2 = *(const bf16x4*)(src + 64 + i);
        float c[4] = {c4.x, c4.y, c4.z, c4.w};
        float sn[4] = {s4.x, s4.y, s4.z, s4.w};
        bf16x4 o1, o2;
        if (isQ) {
#pragma unroll
            for (int k = 0; k < 4; ++k) {
                float a = (float)x1[k], bv = (float)x2[k];
                o1[k] = (__bf16)((a * c[k] - bv * sn[k]) * ATT_SCALE);
                o2[k] = (__bf16)((bv * c[k] + a * sn[k]) * ATT_SCALE);
            }
            size_t o = ((size_t)(b * 32 + head) * S_LEN + s) * HDIM + i;
            *(bf16x4*)(Qb + o)      = o1;
            *(bf16x4*)(Qb + o + 64) = o2;
        } else {
#pragma unroll
            for (int k = 0; k < 4; ++k) {
                float a = (float)x1[k], bv = (float)x2[k];
                o1[k] = (__bf16)(a * c[k] - bv * sn[k]);
                o2[k] = (__bf16)(bv * c[k] + a * sn[k]);
            }
            int g = head - 32;
            size_t o = ((size_t)(b * 8 + g) * S_LEN + s) * HDIM + i;
            *(bf16x4*)(Kb + o)      = o1;
            *(bf16x4*)(Kb + o + 64) = o2;
        }
    }
}

// ---------------- Flash attention (causal, GQA rep=4) ----------------
// Paired q-tiles (qt=p and 7-p; grid 256 = one balanced round). QBLK=256
// (8 waves x 32 q-rows), KVBLK=64. Quad-buffered K/V (128KB LDS), depth-3
// counted vmcnt + raw barrier pairs. Swapped QK^T + swapped PV, in-register
// P transpose via permlane swaps.
__global__ __launch_bounds__(512, 2) void attn_kernel(const __bf16* __restrict__ Q,
                                                      const __bf16* __restrict__ K,
                                                      const __bf16* __restrict__ Vt,
                                                      __bf16* __restrict__ O) {
    const int tid = threadIdx.x;
    const int w = tid >> 6, l = tid & 63;
    const int l15 = l & 15, l4 = l >> 4;
    const int flat = blockIdx.x + (blockIdx.y << 2) + (blockIdx.z << 7);  // 0..255
    const int swz = (flat & 7) * 32 + (flat >> 3);
    const int p = swz & 3;
    const int hb = swz >> 2;
    const int h = hb & 31, b = hb >> 5;
    const int g = h >> 2;

    __shared__ __bf16 Ks[4][64 * 128];   // 4x16 KB; chunk c: row=c>>4, cc=(c&15)^(row&7)
    __shared__ __bf16 Vs[4][128 * 64];   // 4x16 KB; chunk c: row=c>>3, cc=(c&7)^(row&7)

    const __bf16* Kp = K + (size_t)(b * 8 + g) * S_LEN * HDIM;
    const __bf16* Vp = Vt + (size_t)(b * 8 + g) * HDIM * S_LEN;

#define RED16(x, OPINS) do {                                                      \
        u32 ra_ = __builtin_bit_cast(u32, x), rb_;                                \
        asm("v_mov_b32 %0, %1" : "=v"(rb_) : "v"(ra_));                           \
        asm("v_permlane16_swap_b32 %0, %1" : "+v"(ra_), "+v"(rb_));               \
        x = OPINS(__builtin_bit_cast(float, ra_), __builtin_bit_cast(float, rb_));\
    } while (0)
#define RED32(x, OPINS) do {                                                      \
        u32 ra_ = __builtin_bit_cast(u32, x), rb_;                                \
        asm("v_mov_b32 %0, %1" : "=v"(rb_) : "v"(ra_));                           \
        asm("v_permlane32_swap_b32 %0, %1" : "+v"(ra_), "+v"(rb_));               \
        x = OPINS(__builtin_bit_cast(float, ra_), __builtin_bit_cast(float, rb_));\
    } while (0)
#define FADD_(a_, b_) ((a_) + (b_))

#define STAGE(ktile) do {                                                          \
        const int buf_ = (ktile) & 3;                                              \
        const __bf16* kbase = Kp + (size_t)(ktile) * 64 * HDIM;                    \
        _Pragma("unroll")                                                          \
        for (int i_ = 0; i_ < 2; ++i_) {                                           \
            int c_ = i_ * 512 + tid;            /* 1024 chunks = 64x128 bf16 */    \
            int row_ = c_ >> 4, cc_ = (c_ & 15) ^ (row_ & 7);                      \
            GLDS16(kbase + (size_t)row_ * HDIM + cc_ * 8,                          \
                   (char*)Ks[buf_] + c_ * 16);                                     \
        }                                                                          \
        const __bf16* vbase = Vp + (size_t)(ktile) * 64;                           \
        _Pragma("unroll")                                                          \
        for (int i_ = 0; i_ < 2; ++i_) {                                           \
            int c_ = i_ * 512 + tid;            /* 1024 chunks = 128x64 bf16 */    \
            int row_ = c_ >> 3, cc_ = (c_ & 7) ^ (row_ & 7);                       \
            GLDS16(vbase + (size_t)row_ * S_LEN + cc_ * 8,                         \
                   (char*)Vs[buf_] + c_ * 16);                                     \
        }                                                                          \
    } while (0)

    for (int pi = 0; pi < 2; ++pi) {
        const int qt = pi ? (7 - p) : p;
        const int qw0 = qt * 256 + w * 32;       // wave's first q-row
        const __bf16* Qp = Q + ((size_t)((b * 32 + h) * S_LEN + qw0)) * HDIM;

        bf16x8 qf[2][4];
#pragma unroll
        for (int qh = 0; qh < 2; ++qh)
#pragma unroll
            for (int kk = 0; kk < 4; ++kk)
                qf[qh][kk] = *(const bf16x8*)(Qp + (size_t)(qh * 16 + l15) * HDIM + kk * 32 + l4 * 8);

        f32x4 acc[2][8] = {};   // [qh][n]: D[d = n*16 + l4*4 + r][q = qw0+qh*16+l15]
        float m[2]    = {-1e30f, -1e30f};
        float lsum[2] = {0.f, 0.f};

        const int nkt = 4 * qt + 4;
        // pass-2 entry: retire pass-1 epilogue stores so counted vmcnt stays exact
        if (pi) { asm volatile("s_waitcnt vmcnt(0)" ::: "memory"); }
        STAGE(0);
        STAGE(1);
        STAGE(2);

        for (int kt = 0; kt < nkt; ++kt) {
            if (kt + 3 < nkt) STAGE(kt + 3);
            {
                int rem = nkt - 1 - kt;
                if (rem >= 3)      { asm volatile("s_waitcnt vmcnt(12)" ::: "memory"); }
                else if (rem == 2) { asm volatile("s_waitcnt vmcnt(8)"  ::: "memory"); }
                else if (rem == 1) { asm volatile("s_waitcnt vmcnt(4)"  ::: "memory"); }
                else               { asm volatile("s_waitcnt vmcnt(0)"  ::: "memory"); }
            }
            __builtin_amdgcn_sched_barrier(0);
            __builtin_amdgcn_s_barrier();      // barrier#1: tile kt visible to all
            __builtin_amdgcn_sched_barrier(0);
            const int cur = kt & 3;
            if (kt * 64 <= qw0 + 31) {         // wave-level causal skip
                f32x4 sfr[2][4];
                __builtin_amdgcn_s_setprio(1);
#pragma unroll
                for (int fn = 0; fn < 4; ++fn) {
                    f32x4 sa0 = {}, sa1 = {};
#pragma unroll
                    for (int kk = 0; kk < 4; ++kk) {
                        int row = fn * 16 + l15;
                        int cc = (kk * 4 + l4) ^ (l15 & 7);
                        bf16x8 kb = *(const bf16x8*)(Ks[cur] + row * HDIM + cc * 8);
                        sa0 = __builtin_amdgcn_mfma_f32_16x16x32_bf16(kb, qf[0][kk], sa0, 0, 0, 0);
                        sa1 = __builtin_amdgcn_mfma_f32_16x16x32_bf16(kb, qf[1][kk], sa1, 0, 0, 0);
                    }
                    sfr[0][fn] = sa0; sfr[1][fn] = sa1;
                }
                __builtin_amdgcn_s_setprio(0);
                const bool needmask = (kt * 64 + 63 > qw0);
                bf16x8 pb[2][2];
#pragma unroll
                for (int qh = 0; qh < 2; ++qh) {
                    const int qrow = qw0 + qh * 16 + l15;
                    float pmax = -1e30f;
#pragma unroll
                    for (int fn = 0; fn < 4; ++fn)
#pragma unroll
                        for (int r = 0; r < 4; ++r) {
                            float v = sfr[qh][fn][r];
                            if (needmask) {
                                int kcol = kt * 64 + fn * 16 + l4 * 4 + r;
                                if (kcol > qrow) v = -1e30f;
                            }
                            sfr[qh][fn][r] = v;
                            pmax = fmaxf(pmax, v);
                        }
                    RED16(pmax, fmaxf);
                    RED32(pmax, fmaxf);
                    if (!__all(pmax - m[qh] <= 8.0f)) {          // defer-max (rare)
                        float mn = fmaxf(m[qh], pmax);
                        float alpha = exp2f((m[qh] - mn) * L2E);
                        m[qh] = mn;
                        lsum[qh] *= alpha;
#pragma unroll
                        for (int n = 0; n < 8; ++n)
#pragma unroll
                            for (int r = 0; r < 4; ++r) acc[qh][n][r] *= alpha;
                    }
                    float rs = 0.f;
                    u32 pk01[4], pk23[4];
#pragma unroll
                    for (int fn = 0; fn < 4; ++fn) {
                        float p0 = exp2f((sfr[qh][fn][0] - m[qh]) * L2E);
                        float p1 = exp2f((sfr[qh][fn][1] - m[qh]) * L2E);
                        float p2 = exp2f((sfr[qh][fn][2] - m[qh]) * L2E);
                        float p3 = exp2f((sfr[qh][fn][3] - m[qh]) * L2E);
                        rs += (p0 + p1) + (p2 + p3);
                        asm("v_cvt_pk_bf16_f32 %0, %1, %2" : "=v"(pk01[fn]) : "v"(p0), "v"(p1));
                        asm("v_cvt_pk_bf16_f32 %0, %1, %2" : "=v"(pk23[fn]) : "v"(p2), "v"(p3));
                    }
                    RED16(rs, FADD_);
                    RED32(rs, FADD_);
                    lsum[qh] += rs;
#pragma unroll
                    for (int kk = 0; kk < 2; ++kk) {
                        u32 w0 = pk01[2 * kk], w2 = pk01[2 * kk + 1];
                        asm("v_permlane32_swap_b32 %0, %1" : "+v"(w0), "+v"(w2));
                        asm("v_permlane16_swap_b32 %0, %1" : "+v"(w0), "+v"(w2));
                        u32 w1 = pk23[2 * kk], w3 = pk23[2 * kk + 1];
                        asm("v_permlane32_swap_b32 %0, %1" : "+v"(w1), "+v"(w3));
                        asm("v_permlane16_swap_b32 %0, %1" : "+v"(w1), "+v"(w3));
                        u32x4 wv;
                        wv[0] = w0; wv[1] = w1; wv[2] = w2; wv[3] = w3;
                        pb[qh][kk] = __builtin_bit_cast(bf16x8, wv);
                    }
                }
                __builtin_amdgcn_s_setprio(1);
#pragma unroll
                for (int kk = 0; kk < 2; ++kk) {
#pragma unroll
                    for (int n = 0; n < 8; ++n) {
                        int row = n * 16 + l15;
                        int cc = (kk * 4 + l4) ^ (l15 & 7);
                        bf16x8 vb = *(const bf16x8*)(Vs[cur] + row * 64 + cc * 8);
                        acc[0][n] = __builtin_amdgcn_mfma_f32_16x16x32_bf16(vb, pb[0][kk], acc[0][n], 0, 0, 0);
                        acc[1][n] = __builtin_amdgcn_mfma_f32_16x16x32_bf16(vb, pb[1][kk], acc[1][n], 0, 0, 0);
                    }
                }
                __builtin_amdgcn_s_setprio(0);
            }
            __builtin_amdgcn_sched_barrier(0);
            __builtin_amdgcn_s_barrier();      // barrier#2: reads of slot kt done
            __builtin_amdgcn_sched_barrier(0);
        }
        // ---- epilogue: attn[b, q, h*128 + d], d = n*16 + l4*4 + r ----
#pragma unroll
        for (int qh = 0; qh < 2; ++qh) {
            float inv = 1.0f / lsum[qh];
            int qrow = qw0 + qh * 16 + l15;
            __bf16* obase = O + ((size_t)(b * S_LEN) + qrow) * QSZ + h * HDIM + l4 * 4;
#pragma unroll
            for (int n = 0; n < 8; ++n) {
                bf16x4 o4;
#pragma unroll
                for (int r = 0; r < 4; ++r) o4[r] = (__bf16)(acc[qh][n][r] * inv);
                *(bf16x4*)(obase + n * 16) = o4;
            }
        }
    }
#undef STAGE
#undef RED16
#undef RED32
#undef FADD_
}

extern "C" void kernel_launch(void* const* d_in, const int* in_sizes, int n_in,
                              void* d_out, int out_size, void* d_ws, size_t ws_size,
                              hipStream_t stream) {
    const int*   pos    = (const int*)d_in[0];
    const float* hidden = (const float*)d_in[1];
    const float* wqkv   = (const float*)d_in[2];
    const float* wo     = (const float*)d_in[3];
    float* out = (float*)d_out;

    // workspace carve
    __bf16* hb    = (__bf16*)d_ws;                     // 16,777,216 elems
    __bf16* wqb   = hb  + 16777216;                    // 25,165,824
    __bf16* wob   = wqb + 25165824;                    // 16,777,216
    __bf16* qkv   = wob + 16777216;                    // 25,165,824 bf16 (V slice unused)
    __bf16* Qb    = qkv + 25165824;                    // 16,777,216
    __bf16* Kb    = Qb  + 16777216;                    // 4,194,304
    __bf16* Vtb   = Kb  + 4194304;                     // 4,194,304
    __bf16* attnb = Vtb + 4194304;                     // 16,777,216
    float*  rc    = (float*)(attnb + 16777216);        // 131,072
    float*  rs    = rc + 131072;                       // 131,072

    conv3_f32_bf16<<<2048, 256, 0, stream>>>(hidden, hb, 4194304,
                                             wqkv, wqb, 6291456,
                                             wo, wob, 4194304);
    rope_table_kernel<<<512, 256, 0, stream>>>(rc, rs);
    gemm256<__bf16, true><<<dim3(QKVSZ / 256, (B_DIM * S_LEN) / 256), 512, 0, stream>>>(
        hb, wqb, qkv, Vtb, QKVSZ);
    rope_kernel<<<B_DIM * S_LEN, 256, 0, stream>>>(qkv, pos, rc, rs, Qb, Kb);
    attn_kernel<<<dim3(4, NHEADS, B_DIM), 512, 0, stream>>>(Qb, Kb, Vtb, attnb);
    gemm256<float, false><<<dim3(HIDDEN / 256, (B_DIM * S_LEN) / 256), 512, 0, stream>>>(
        attnb, wob, out, nullptr, HIDDEN);
}

// Round 20
// 504.781 us; speedup vs baseline: 1.0512x; 1.0202x over previous
//
#include <hip/hip_runtime.h>
#include <hip/hip_bf16.h>
#include <cmath>

typedef __bf16 bf16x8 __attribute__((ext_vector_type(8)));
typedef __bf16 bf16x4 __attribute__((ext_vector_type(4)));
typedef float  f32x4  __attribute__((ext_vector_type(4)));
typedef unsigned int u32;
typedef u32 u32x4 __attribute__((ext_vector_type(4)));

#define AS1 __attribute__((address_space(1)))
#define AS3 __attribute__((address_space(3)))
#define GLDS16(gp, lp) __builtin_amdgcn_global_load_lds((AS1 void*)(gp), (AS3 void*)(lp), 16, 0, 0)

#define B_DIM 2
#define S_LEN 2048
#define HIDDEN 4096
#define NHEADS 32
#define NKV 8
#define HDIM 128
#define QSZ 4096
#define KVSZ 1024
#define QKVSZ 6144
#define GK 4096                /* K of both GEMMs */
#define ATT_SCALE 0.0078125f   /* 1/128, folded into Qb in fused epilogue */
#define L2E 1.4426950408889634f

// ---------------- merged f32 -> bf16 conversion (3 buffers, grid-stride) ----------------
__global__ __launch_bounds__(256) void conv3_f32_bf16(const float* __restrict__ i0, __bf16* __restrict__ o0, int n0,
                                                      const float* __restrict__ i1, __bf16* __restrict__ o1, int n1,
                                                      const float* __restrict__ i2, __bf16* __restrict__ o2, int n2) {
    const int total = n0 + n1 + n2;
    for (int idx = blockIdx.x * 256 + threadIdx.x; idx < total; idx += gridDim.x * 256) {
        const float* in; __bf16* out; int j = idx;
        if (j < n0) { in = i0; out = o0; }
        else if ((j -= n0) < n1) { in = i1; out = o1; }
        else { j -= n1; in = i2; out = o2; }
        float4 v = ((const float4*)in)[j];
        bf16x4 o;
        o[0] = (__bf16)v.x; o[1] = (__bf16)v.y; o[2] = (__bf16)v.z; o[3] = (__bf16)v.w;
        ((bf16x4*)out)[j] = o;
    }
}

// ---------------- RoPE cos/sin table: [pos][i], i<64 ----------------
__global__ __launch_bounds__(256) void rope_table_kernel(float* __restrict__ ct,
                                                         float* __restrict__ st) {
    int idx = blockIdx.x * 256 + threadIdx.x;   // S_LEN*64 entries
    int p = idx >> 6, i = idx & 63;
    float inv = expf(-(float)i * (9.210340371976184f / 64.0f));
    float freq = (float)p * inv;
    float s, c;
    sincosf(freq, &s, &c);
    ct[idx] = c; st[idx] = s;
}

// ---------------- 256x256 4-phase/K-tile GEMM (R18 schedule, B-residency) ----------------
// MODE 0: plain C store (O-projection).
// MODE 1: fused QKV epilogue — V blocks (n0>=5120) write transposed into Vt;
//         Q/K blocks exchange acc through LDS and apply RoPE, writing Qb/Kb
//         directly (no qkv round-trip, no rope kernel).
template<typename OUT, int MODE>
__global__ __launch_bounds__(512, 2) void gemm256(const __bf16* __restrict__ A,
                                                  const __bf16* __restrict__ B,
                                                  OUT* __restrict__ C,
                                                  __bf16* __restrict__ Vt,
                                                  __bf16* __restrict__ Qb,
                                                  __bf16* __restrict__ Kb,
                                                  const int* __restrict__ pos,
                                                  const float* __restrict__ ct,
                                                  const float* __restrict__ st,
                                                  int N) {
    __shared__ __bf16 Asm[2 * 16384 + 2 * 16384];   // A: 2 slots x 32KB, B: 2 slots x 32KB
    char* Bbase = (char*)Asm + 65536;

    const int tid = threadIdx.x;
    const int w = tid >> 6, l = tid & 63;
    const int l15 = l & 15, l4 = l >> 4;
    const int wr = w >> 2, wc = w & 3;

    const int nwg = gridDim.x * gridDim.y;
    const int orig = blockIdx.y * gridDim.x + blockIdx.x;
    const int swz = (orig & 7) * (nwg >> 3) + (orig >> 3);
    const int bx = swz % gridDim.x, by = swz / gridDim.x;
    const int m0 = by * 256, n0 = bx * 256;

    const __bf16* Ag = A + (size_t)m0 * GK;
    const __bf16* Bg = B + (size_t)n0 * GK;

#define STAGE_AQ(q, tile) do {                                                  \
        int c_ = (q) * 512 + tid;                                               \
        int r_ = c_ >> 3;                                                       \
        int jg_ = (tid & 7) ^ (r_ & 7);                                         \
        GLDS16(Ag + (size_t)r_ * GK + (tile) * 64 + jg_ * 8,                    \
               (char*)Asm + ((tile) & 1) * 32768 + c_ * 16);                    \
    } while (0)
#define STAGE_BS(s, tile) do {                                                  \
        _Pragma("unroll")                                                       \
        for (int i_ = 0; i_ < 2; ++i_) {                                        \
            int v_ = i_ * 512 + tid;                                            \
            int r_ = (v_ >> 8) * 64 + (s) * 32 + ((v_ >> 3) & 31);              \
            int jg_ = (v_ & 7) ^ (r_ & 7);                                      \
            int c_ = r_ * 8 + (v_ & 7);                                         \
            GLDS16(Bg + (size_t)r_ * GK + (tile) * 64 + jg_ * 8,                \
                   Bbase + ((tile) & 1) * 32768 + c_ * 16);                     \
        }                                                                       \
    } while (0)

#define LOAD_A(DST, MH) do {                                                    \
        _Pragma("unroll")                                                       \
        for (int m2 = 0; m2 < 4; ++m2) {                                        \
            int row = wr * 128 + ((MH) * 4 + m2) * 16 + l15;                    \
            _Pragma("unroll")                                                   \
            for (int kk = 0; kk < 2; ++kk) {                                    \
                int j = (kk * 4 + l4) ^ (row & 7);                              \
                DST[m2][kk] = *(const bf16x8*)(Als + row * 64 + j * 8);         \
            }                                                                   \
        }                                                                       \
    } while (0)
#define LOAD_B(DST, NH) do {                                                    \
        _Pragma("unroll")                                                       \
        for (int n2 = 0; n2 < 2; ++n2) {                                        \
            int row = wc * 64 + ((NH) * 2 + n2) * 16 + l15;                     \
            _Pragma("unroll")                                                   \
            for (int kk = 0; kk < 2; ++kk) {                                    \
                int j = (kk * 4 + l4) ^ (row & 7);                              \
                DST[n2][kk] = *(const bf16x8*)(Bls + row * 64 + j * 8);         \
            }                                                                   \
        }                                                                       \
    } while (0)
#define MFMA_QUAD(AF, BF, MI0, NI0)                                             \
    _Pragma("unroll")                                                           \
    for (int m2 = 0; m2 < 4; ++m2)                                              \
        _Pragma("unroll")                                                       \
        for (int n2 = 0; n2 < 2; ++n2)                                          \
            _Pragma("unroll")                                                   \
            for (int kk = 0; kk < 2; ++kk)                                      \
                acc[(MI0) + m2][(NI0) + n2] =                                   \
                    __builtin_amdgcn_mfma_f32_16x16x32_bf16(                    \
                        AF[m2][kk], BF[n2][kk], acc[(MI0) + m2][(NI0) + n2], 0, 0, 0);

    f32x4 acc[8][4] = {};

    const int T = GK / 64;   // 64 K-tiles
    STAGE_AQ(0, 0); STAGE_AQ(1, 0); STAGE_AQ(2, 0); STAGE_AQ(3, 0);
    STAGE_BS(0, 0); STAGE_BS(1, 0);
    STAGE_AQ(0, 1); STAGE_AQ(2, 1); STAGE_BS(0, 1);
    asm volatile("s_waitcnt vmcnt(4)" ::: "memory");
    __builtin_amdgcn_s_barrier();

    for (int t = 0; t < T; ++t) {
        const __bf16* Als = Asm + (t & 1) * 16384;
        const __bf16* Bls = (__bf16*)Bbase + (t & 1) * 16384;
        bf16x8 af0[4][2], af1[4][2], bA[2][2], bB[2][2];
        // ---- ph0: MH0 x NH0 ---- (af0 lives through ph1; bA through ph2)
        LOAD_A(af0, 0);
        LOAD_B(bA, 0);
        if (t + 1 < T) { STAGE_AQ(1, t + 1); STAGE_AQ(3, t + 1); }
        __builtin_amdgcn_s_barrier();
        __builtin_amdgcn_s_setprio(1);
        MFMA_QUAD(af0, bA, 0, 0);
        __builtin_amdgcn_s_setprio(0);
        __builtin_amdgcn_s_barrier();
        // ---- ph1: MH0 x NH1 ---- (bB lives through ph3)
        LOAD_B(bB, 1);
        if (t + 1 < T) STAGE_BS(1, t + 1);
        __builtin_amdgcn_s_barrier();
        __builtin_amdgcn_s_setprio(1);
        MFMA_QUAD(af0, bB, 0, 2);
        __builtin_amdgcn_s_setprio(0);
        __builtin_amdgcn_s_barrier();
        // ---- ph2: MH1 x NH0 ---- (reuse bA; no B reload)
        LOAD_A(af1, 1);
        if (t + 2 < T) { STAGE_AQ(0, t + 2); STAGE_AQ(2, t + 2); }
        __builtin_amdgcn_s_barrier();
        __builtin_amdgcn_s_setprio(1);
        MFMA_QUAD(af1, bA, 4, 0);
        __builtin_amdgcn_s_setprio(0);
        __builtin_amdgcn_s_barrier();
        // ---- ph3: MH1 x NH1 ---- (reuse bB; no ds_reads at all)
        if (t + 2 < T) STAGE_BS(0, t + 2);
        __builtin_amdgcn_s_barrier();
        __builtin_amdgcn_s_setprio(1);
        MFMA_QUAD(af1, bB, 4, 2);
        __builtin_amdgcn_s_setprio(0);
        if (t + 2 < T)      { asm volatile("s_waitcnt vmcnt(4)" ::: "memory"); }
        else if (t + 1 < T) { asm volatile("s_waitcnt vmcnt(0)" ::: "memory"); }
        __builtin_amdgcn_s_barrier();
    }
#undef MFMA_QUAD
#undef LOAD_A
#undef LOAD_B
#undef STAGE_AQ
#undef STAGE_BS

    if (MODE == 1) {
        if (n0 >= QSZ + KVSZ) {
            // V-slice block: write transposed into Vt [B*8, 128, S_LEN]
#pragma unroll
            for (int mi = 0; mi < 8; ++mi) {
                int s0 = m0 + wr * 128 + mi * 16 + l4 * 4;   // 4 consecutive tokens
                int b = s0 >> 11, s = s0 & 2047;
#pragma unroll
                for (int ni = 0; ni < 4; ++ni) {
                    int vcol = n0 - (QSZ + KVSZ) + wc * 64 + ni * 16 + l15;
                    int g = vcol >> 7, d = vcol & 127;
                    bf16x4 o4;
#pragma unroll
                    for (int r = 0; r < 4; ++r) o4[r] = (__bf16)acc[mi][ni][r];
                    *(bf16x4*)(Vt + ((size_t)((b * 8 + g) * HDIM + d)) * S_LEN + s) = o4;
                }
            }
        } else {
            // Q/K block: exchange through (now-dead) staging LDS, apply RoPE.
            __bf16* X = (__bf16*)Asm;   // [256][256] bf16 = 128 KB
            __syncthreads();
#pragma unroll
            for (int mi = 0; mi < 8; ++mi)
#pragma unroll
                for (int ni = 0; ni < 4; ++ni)
#pragma unroll
                    for (int r = 0; r < 4; ++r)
                        X[(wr * 128 + mi * 16 + l4 * 4 + r) * 256
                          + wc * 64 + ni * 16 + l15] = (__bf16)acc[mi][ni][r];
            __syncthreads();
            const bool isQ = (n0 < QSZ);
#pragma unroll
            for (int it = 0; it < 16; ++it) {
                int idx = it * 512 + tid;        // 256 tok x 2 heads x 16 quads
                int q4 = (idx & 15) * 4;
                int hh = (idx >> 4) & 1;
                int lt = idx >> 5;
                int tok = m0 + lt;
                int bb = tok >> 11, ss = tok & 2047;
                int pp = pos[tok];
                float4 c4 = *(const float4*)(ct + (size_t)pp * 64 + q4);
                float4 s4 = *(const float4*)(st + (size_t)pp * 64 + q4);
                bf16x4 x1 = *(const bf16x4*)(X + lt * 256 + hh * 128 + q4);
                bf16x4 x2 = *(const bf16x4*)(X + lt * 256 + hh * 128 + 64 + q4);
                float cc[4] = {c4.x, c4.y, c4.z, c4.w};
                float sn[4] = {s4.x, s4.y, s4.z, s4.w};
                bf16x4 o1, o2;
                if (isQ) {
#pragma unroll
                    for (int k = 0; k < 4; ++k) {
                        float a = (float)x1[k], bv = (float)x2[k];
                        o1[k] = (__bf16)((a * cc[k] - bv * sn[k]) * ATT_SCALE);
                        o2[k] = (__bf16)((bv * cc[k] + a * sn[k]) * ATT_SCALE);
                    }
                    int gh = (n0 >> 7) + hh;
                    size_t o = ((size_t)(bb * 32 + gh) * S_LEN + ss) * HDIM + q4;
                    *(bf16x4*)(Qb + o)      = o1;
                    *(bf16x4*)(Qb + o + 64) = o2;
                } else {
#pragma unroll
                    for (int k = 0; k < 4; ++k) {
                        float a = (float)x1[k], bv = (float)x2[k];
                        o1[k] = (__bf16)(a * cc[k] - bv * sn[k]);
                        o2[k] = (__bf16)(bv * cc[k] + a * sn[k]);
                    }
                    int gk = ((n0 - QSZ) >> 7) + hh;
                    size_t o = ((size_t)(bb * 8 + gk) * S_LEN + ss) * HDIM + q4;
                    *(bf16x4*)(Kb + o)      = o1;
                    *(bf16x4*)(Kb + o + 64) = o2;
                }
            }
        }
    } else {
#pragma unroll
        for (int mi = 0; mi < 8; ++mi)
#pragma unroll
            for (int ni = 0; ni < 4; ++ni)
#pragma unroll
                for (int r = 0; r < 4; ++r)
                    C[(size_t)(m0 + wr * 128 + mi * 16 + l4 * 4 + r) * N
                      + n0 + wc * 64 + ni * 16 + l15] = (OUT)acc[mi][ni][r];
    }
}

// ---------------- Flash attention (causal, GQA rep=4) ----------------
// Paired q-tiles (qt=p and 7-p; grid 256 = one balanced round). QBLK=256
// (8 waves x 32 q-rows), KVBLK=64. Quad-buffered K/V (128KB LDS), depth-3
// counted vmcnt + raw barrier pairs. Swapped QK^T + swapped PV, in-register
// P transpose via permlane swaps.
__global__ __launch_bounds__(512, 2) void attn_kernel(const __bf16* __restrict__ Q,
                                                      const __bf16* __restrict__ K,
                                                      const __bf16* __restrict__ Vt,
                                                      __bf16* __restrict__ O) {
    const int tid = threadIdx.x;
    const int w = tid >> 6, l = tid & 63;
    const int l15 = l & 15, l4 = l >> 4;
    const int flat = blockIdx.x + (blockIdx.y << 2) + (blockIdx.z << 7);  // 0..255
    const int swz = (flat & 7) * 32 + (flat >> 3);
    const int p = swz & 3;
    const int hb = swz >> 2;
    const int h = hb & 31, b = hb >> 5;
    const int g = h >> 2;

    __shared__ __bf16 Ks[4][64 * 128];   // 4x16 KB; chunk c: row=c>>4, cc=(c&15)^(row&7)
    __shared__ __bf16 Vs[4][128 * 64];   // 4x16 KB; chunk c: row=c>>3, cc=(c&7)^(row&7)

    const __bf16* Kp = K + (size_t)(b * 8 + g) * S_LEN * HDIM;
    const __bf16* Vp = Vt + (size_t)(b * 8 + g) * HDIM * S_LEN;

#define RED16(x, OPINS) do {                                                      \
        u32 ra_ = __builtin_bit_cast(u32, x), rb_;                                \
        asm("v_mov_b32 %0, %1" : "=v"(rb_) : "v"(ra_));                           \
        asm("v_permlane16_swap_b32 %0, %1" : "+v"(ra_), "+v"(rb_));               \
        x = OPINS(__builtin_bit_cast(float, ra_), __builtin_bit_cast(float, rb_));\
    } while (0)
#define RED32(x, OPINS) do {                                                      \
        u32 ra_ = __builtin_bit_cast(u32, x), rb_;                                \
        asm("v_mov_b32 %0, %1" : "=v"(rb_) : "v"(ra_));                           \
        asm("v_permlane32_swap_b32 %0, %1" : "+v"(ra_), "+v"(rb_));               \
        x = OPINS(__builtin_bit_cast(float, ra_), __builtin_bit_cast(float, rb_));\
    } while (0)
#define FADD_(a_, b_) ((a_) + (b_))

#define STAGE(ktile) do {                                                          \
        const int buf_ = (ktile) & 3;                                              \
        const __bf16* kbase = Kp + (size_t)(ktile) * 64 * HDIM;                    \
        _Pragma("unroll")                                                          \
        for (int i_ = 0; i_ < 2; ++i_) {                                           \
            int c_ = i_ * 512 + tid;            /* 1024 chunks = 64x128 bf16 */    \
            int row_ = c_ >> 4, cc_ = (c_ & 15) ^ (row_ & 7);                      \
            GLDS16(kbase + (size_t)row_ * HDIM + cc_ * 8,                          \
                   (char*)Ks[buf_] + c_ * 16);                                     \
        }                                                                          \
        const __bf16* vbase = Vp + (size_t)(ktile) * 64;                           \
        _Pragma("unroll")                                                          \
        for (int i_ = 0; i_ < 2; ++i_) {                                           \
            int c_ = i_ * 512 + tid;            /* 1024 chunks = 128x64 bf16 */    \
            int row_ = c_ >> 3, cc_ = (c_ & 7) ^ (row_ & 7);                       \
            GLDS16(vbase + (size_t)row_ * S_LEN + cc_ * 8,                         \
                   (char*)Vs[buf_] + c_ * 16);                                     \
        }                                                                          \
    } while (0)

    for (int pi = 0; pi < 2; ++pi) {
        const int qt = pi ? (7 - p) : p;
        const int qw0 = qt * 256 + w * 32;       // wave's first q-row
        const __bf16* Qp = Q + ((size_t)((b * 32 + h) * S_LEN + qw0)) * HDIM;

        bf16x8 qf[2][4];
#pragma unroll
        for (int qh = 0; qh < 2; ++qh)
#pragma unroll
            for (int kk = 0; kk < 4; ++kk)
                qf[qh][kk] = *(const bf16x8*)(Qp + (size_t)(qh * 16 + l15) * HDIM + kk * 32 + l4 * 8);

        f32x4 acc[2][8] = {};   // [qh][n]: D[d = n*16 + l4*4 + r][q = qw0+qh*16+l15]
        float m[2]    = {-1e30f, -1e30f};
        float lsum[2] = {0.f, 0.f};

        const int nkt = 4 * qt + 4;
        // pass-2 entry: retire pass-1 epilogue stores so counted vmcnt stays exact
        if (pi) { asm volatile("s_waitcnt vmcnt(0)" ::: "memory"); }
        STAGE(0);
        STAGE(1);
        STAGE(2);

        for (int kt = 0; kt < nkt; ++kt) {
            if (kt + 3 < nkt) STAGE(kt + 3);
            {
                int rem = nkt - 1 - kt;
                if (rem >= 3)      { asm volatile("s_waitcnt vmcnt(12)" ::: "memory"); }
                else if (rem == 2) { asm volatile("s_waitcnt vmcnt(8)"  ::: "memory"); }
                else if (rem == 1) { asm volatile("s_waitcnt vmcnt(4)"  ::: "memory"); }
                else               { asm volatile("s_waitcnt vmcnt(0)"  ::: "memory"); }
            }
            __builtin_amdgcn_sched_barrier(0);
            __builtin_amdgcn_s_barrier();      // barrier#1: tile kt visible to all
            __builtin_amdgcn_sched_barrier(0);
            const int cur = kt & 3;
            if (kt * 64 <= qw0 + 31) {         // wave-level causal skip
                f32x4 sfr[2][4];
                __builtin_amdgcn_s_setprio(1);
#pragma unroll
                for (int fn = 0; fn < 4; ++fn) {
                    f32x4 sa0 = {}, sa1 = {};
#pragma unroll
                    for (int kk = 0; kk < 4; ++kk) {
                        int row = fn * 16 + l15;
                        int cc = (kk * 4 + l4) ^ (l15 & 7);
                        bf16x8 kb = *(const bf16x8*)(Ks[cur] + row * HDIM + cc * 8);
                        sa0 = __builtin_amdgcn_mfma_f32_16x16x32_bf16(kb, qf[0][kk], sa0, 0, 0, 0);
                        sa1 = __builtin_amdgcn_mfma_f32_16x16x32_bf16(kb, qf[1][kk], sa1, 0, 0, 0);
                    }
                    sfr[0][fn] = sa0; sfr[1][fn] = sa1;
                }
                __builtin_amdgcn_s_setprio(0);
                const bool needmask = (kt * 64 + 63 > qw0);
                bf16x8 pb[2][2];
#pragma unroll
                for (int qh = 0; qh < 2; ++qh) {
                    const int qrow = qw0 + qh * 16 + l15;
                    float pmax = -1e30f;
#pragma unroll
                    for (int fn = 0; fn < 4; ++fn)
#pragma unroll
                        for (int r = 0; r < 4; ++r) {
                            float v = sfr[qh][fn][r];
                            if (needmask) {
                                int kcol = kt * 64 + fn * 16 + l4 * 4 + r;
                                if (kcol > qrow) v = -1e30f;
                            }
                            sfr[qh][fn][r] = v;
                            pmax = fmaxf(pmax, v);
                        }
                    RED16(pmax, fmaxf);
                    RED32(pmax, fmaxf);
                    if (!__all(pmax - m[qh] <= 8.0f)) {          // defer-max (rare)
                        float mn = fmaxf(m[qh], pmax);
                        float alpha = exp2f((m[qh] - mn) * L2E);
                        m[qh] = mn;
                        lsum[qh] *= alpha;
#pragma unroll
                        for (int n = 0; n < 8; ++n)
#pragma unroll
                            for (int r = 0; r < 4; ++r) acc[qh][n][r] *= alpha;
                    }
                    float rs = 0.f;
                    u32 pk01[4], pk23[4];
#pragma unroll
                    for (int fn = 0; fn < 4; ++fn) {
                        float p0 = exp2f((sfr[qh][fn][0] - m[qh]) * L2E);
                        float p1 = exp2f((sfr[qh][fn][1] - m[qh]) * L2E);
                        float p2 = exp2f((sfr[qh][fn][2] - m[qh]) * L2E);
                        float p3 = exp2f((sfr[qh][fn][3] - m[qh]) * L2E);
                        rs += (p0 + p1) + (p2 + p3);
                        asm("v_cvt_pk_bf16_f32 %0, %1, %2" : "=v"(pk01[fn]) : "v"(p0), "v"(p1));
                        asm("v_cvt_pk_bf16_f32 %0, %1, %2" : "=v"(pk23[fn]) : "v"(p2), "v"(p3));
                    }
                    RED16(rs, FADD_);
                    RED32(rs, FADD_);
                    lsum[qh] += rs;
#pragma unroll
                    for (int kk = 0; kk < 2; ++kk) {
                        u32 w0 = pk01[2 * kk], w2 = pk01[2 * kk + 1];
                        asm("v_permlane32_swap_b32 %0, %1" : "+v"(w0), "+v"(w2));
                        asm("v_permlane16_swap_b32 %0, %1" : "+v"(w0), "+v"(w2));
                        u32 w1 = pk23[2 * kk], w3 = pk23[2 * kk + 1];
                        asm("v_permlane32_swap_b32 %0, %1" : "+v"(w1), "+v"(w3));
                        asm("v_permlane16_swap_b32 %0, %1" : "+v"(w1), "+v"(w3));
                        u32x4 wv;
                        wv[0] = w0; wv[1] = w1; wv[2] = w2; wv[3] = w3;
                        pb[qh][kk] = __builtin_bit_cast(bf16x8, wv);
                    }
                }
                __builtin_amdgcn_s_setprio(1);
#pragma unroll
                for (int kk = 0; kk < 2; ++kk) {
#pragma unroll
                    for (int n = 0; n < 8; ++n) {
                        int row = n * 16 + l15;
                        int cc = (kk * 4 + l4) ^ (l15 & 7);
                        bf16x8 vb = *(const bf16x8*)(Vs[cur] + row * 64 + cc * 8);
                        acc[0][n] = __builtin_amdgcn_mfma_f32_16x16x32_bf16(vb, pb[0][kk], acc[0][n], 0, 0, 0);
                        acc[1][n] = __builtin_amdgcn_mfma_f32_16x16x32_bf16(vb, pb[1][kk], acc[1][n], 0, 0, 0);
                    }
                }
                __builtin_amdgcn_s_setprio(0);
            }
            __builtin_amdgcn_sched_barrier(0);
            __builtin_amdgcn_s_barrier();      // barrier#2: reads of slot kt done
            __builtin_amdgcn_sched_barrier(0);
        }
        // ---- epilogue: attn[b, q, h*128 + d], d = n*16 + l4*4 + r ----
#pragma unroll
        for (int qh = 0; qh < 2; ++qh) {
            float inv = 1.0f / lsum[qh];
            int qrow = qw0 + qh * 16 + l15;
            __bf16* obase = O + ((size_t)(b * S_LEN) + qrow) * QSZ + h * HDIM + l4 * 4;
#pragma unroll
            for (int n = 0; n < 8; ++n) {
                bf16x4 o4;
#pragma unroll
                for (int r = 0; r < 4; ++r) o4[r] = (__bf16)(acc[qh][n][r] * inv);
                *(bf16x4*)(obase + n * 16) = o4;
            }
        }
    }
#undef STAGE
#undef RED16
#undef RED32
#undef FADD_
}

extern "C" void kernel_launch(void* const* d_in, const int* in_sizes, int n_in,
                              void* d_out, int out_size, void* d_ws, size_t ws_size,
                              hipStream_t stream) {
    const int*   pos    = (const int*)d_in[0];
    const float* hidden = (const float*)d_in[1];
    const float* wqkv   = (const float*)d_in[2];
    const float* wo     = (const float*)d_in[3];
    float* out = (float*)d_out;

    // workspace carve
    __bf16* hb    = (__bf16*)d_ws;                     // 16,777,216 elems
    __bf16* wqb   = hb  + 16777216;                    // 25,165,824
    __bf16* wob   = wqb + 25165824;                    // 16,777,216
    __bf16* Qb    = wob + 16777216;                    // 16,777,216
    __bf16* Kb    = Qb  + 16777216;                    // 4,194,304
    __bf16* Vtb   = Kb  + 4194304;                     // 4,194,304
    __bf16* attnb = Vtb + 4194304;                     // 16,777,216
    float*  rc    = (float*)(attnb + 16777216);        // 131,072
    float*  rs    = rc + 131072;                       // 131,072

    conv3_f32_bf16<<<2048, 256, 0, stream>>>(hidden, hb, 4194304,
                                             wqkv, wqb, 6291456,
                                             wo, wob, 4194304);
    rope_table_kernel<<<512, 256, 0, stream>>>(rc, rs);
    // fused QKV GEMM: V blocks -> Vtb (transposed); Q/K blocks -> RoPE -> Qb/Kb
    gemm256<__bf16, 1><<<dim3(QKVSZ / 256, (B_DIM * S_LEN) / 256), 512, 0, stream>>>(
        hb, wqb, ((__bf16*)nullptr), Vtb, Qb, Kb, pos, rc, rs, QKVSZ);
    attn_kernel<<<dim3(4, NHEADS, B_DIM), 512, 0, stream>>>(Qb, Kb, Vtb, attnb);
    gemm256<float, 0><<<dim3(HIDDEN / 256, (B_DIM * S_LEN) / 256), 512, 0, stream>>>(
        attnb, wob, out, nullptr, nullptr, nullptr, nullptr, nullptr, nullptr, HIDDEN);
}

// Round 21
// 502.664 us; speedup vs baseline: 1.0556x; 1.0042x over previous
//
#include <hip/hip_runtime.h>
#include <hip/hip_bf16.h>
#include <cmath>

typedef __bf16 bf16x8 __attribute__((ext_vector_type(8)));
typedef __bf16 bf16x4 __attribute__((ext_vector_type(4)));
typedef float  f32x4  __attribute__((ext_vector_type(4)));
typedef unsigned int u32;
typedef u32 u32x4 __attribute__((ext_vector_type(4)));

#define AS1 __attribute__((address_space(1)))
#define AS3 __attribute__((address_space(3)))
#define GLDS16(gp, lp) __builtin_amdgcn_global_load_lds((AS1 void*)(gp), (AS3 void*)(lp), 16, 0, 0)

#define B_DIM 2
#define S_LEN 2048
#define HIDDEN 4096
#define NHEADS 32
#define NKV 8
#define HDIM 128
#define QSZ 4096
#define KVSZ 1024
#define QKVSZ 6144
#define GK 4096                /* K of both GEMMs */
#define ATT_SCALE 0.0078125f   /* 1/128, folded into Qb in fused epilogue */
#define L2E 1.4426950408889634f
#define XPITCH 264             /* padded exchange row stride (bf16) */

// ---------------- merged conv (3 buffers) + RoPE table, grid-stride ----------------
__global__ __launch_bounds__(256) void prep_kernel(const float* __restrict__ i0, __bf16* __restrict__ o0, int n0,
                                                   const float* __restrict__ i1, __bf16* __restrict__ o1, int n1,
                                                   const float* __restrict__ i2, __bf16* __restrict__ o2, int n2,
                                                   float* __restrict__ ct, float* __restrict__ st) {
    const int total = n0 + n1 + n2;
    for (int idx = blockIdx.x * 256 + threadIdx.x; idx < total; idx += gridDim.x * 256) {
        const float* in; __bf16* out; int j = idx;
        if (j < n0) { in = i0; out = o0; }
        else if ((j -= n0) < n1) { in = i1; out = o1; }
        else { j -= n1; in = i2; out = o2; }
        float4 v = ((const float4*)in)[j];
        bf16x4 o;
        o[0] = (__bf16)v.x; o[1] = (__bf16)v.y; o[2] = (__bf16)v.z; o[3] = (__bf16)v.w;
        ((bf16x4*)out)[j] = o;
    }
    // rope table: S_LEN*64 entries
    for (int idx = blockIdx.x * 256 + threadIdx.x; idx < S_LEN * 64; idx += gridDim.x * 256) {
        int p = idx >> 6, i = idx & 63;
        float inv = expf(-(float)i * (9.210340371976184f / 64.0f));
        float freq = (float)p * inv;
        float s, c;
        sincosf(freq, &s, &c);
        ct[idx] = c; st[idx] = s;
    }
}

// ---------------- 256x256 4-phase/K-tile GEMM (R18 schedule, B-residency) ----------------
// MODE 0: plain C store (O-projection).
// MODE 1: fused QKV epilogue — V blocks (n0>=5120) write transposed into Vt;
//         Q/K blocks exchange acc through padded LDS and apply RoPE, writing
//         Qb/Kb directly (no qkv round-trip, no rope kernel).
template<typename OUT, int MODE>
__global__ __launch_bounds__(512, 2) void gemm256(const __bf16* __restrict__ A,
                                                  const __bf16* __restrict__ B,
                                                  OUT* __restrict__ C,
                                                  __bf16* __restrict__ Vt,
                                                  __bf16* __restrict__ Qb,
                                                  __bf16* __restrict__ Kb,
                                                  const int* __restrict__ pos,
                                                  const float* __restrict__ ct,
                                                  const float* __restrict__ st,
                                                  int N) {
    // union: staging (128 KB) | RoPE exchange [256][XPITCH] (132 KB)
    __shared__ __bf16 Asm[256 * XPITCH];
    char* Bbase = (char*)Asm + 65536;

    const int tid = threadIdx.x;
    const int w = tid >> 6, l = tid & 63;
    const int l15 = l & 15, l4 = l >> 4;
    const int wr = w >> 2, wc = w & 3;

    const int nwg = gridDim.x * gridDim.y;
    const int orig = blockIdx.y * gridDim.x + blockIdx.x;
    const int swz = (orig & 7) * (nwg >> 3) + (orig >> 3);
    const int bx = swz % gridDim.x, by = swz / gridDim.x;
    const int m0 = by * 256, n0 = bx * 256;

    const __bf16* Ag = A + (size_t)m0 * GK;
    const __bf16* Bg = B + (size_t)n0 * GK;

#define STAGE_AQ(q, tile) do {                                                  \
        int c_ = (q) * 512 + tid;                                               \
        int r_ = c_ >> 3;                                                       \
        int jg_ = (tid & 7) ^ (r_ & 7);                                         \
        GLDS16(Ag + (size_t)r_ * GK + (tile) * 64 + jg_ * 8,                    \
               (char*)Asm + ((tile) & 1) * 32768 + c_ * 16);                    \
    } while (0)
#define STAGE_BS(s, tile) do {                                                  \
        _Pragma("unroll")                                                       \
        for (int i_ = 0; i_ < 2; ++i_) {                                        \
            int v_ = i_ * 512 + tid;                                            \
            int r_ = (v_ >> 8) * 64 + (s) * 32 + ((v_ >> 3) & 31);              \
            int jg_ = (v_ & 7) ^ (r_ & 7);                                      \
            int c_ = r_ * 8 + (v_ & 7);                                         \
            GLDS16(Bg + (size_t)r_ * GK + (tile) * 64 + jg_ * 8,                \
                   Bbase + ((tile) & 1) * 32768 + c_ * 16);                     \
        }                                                                       \
    } while (0)

#define LOAD_A(DST, MH) do {                                                    \
        _Pragma("unroll")                                                       \
        for (int m2 = 0; m2 < 4; ++m2) {                                        \
            int row = wr * 128 + ((MH) * 4 + m2) * 16 + l15;                    \
            _Pragma("unroll")                                                   \
            for (int kk = 0; kk < 2; ++kk) {                                    \
                int j = (kk * 4 + l4) ^ (row & 7);                              \
                DST[m2][kk] = *(const bf16x8*)(Als + row * 64 + j * 8);         \
            }                                                                   \
        }                                                                       \
    } while (0)
#define LOAD_B(DST, NH) do {                                                    \
        _Pragma("unroll")                                                       \
        for (int n2 = 0; n2 < 2; ++n2) {                                        \
            int row = wc * 64 + ((NH) * 2 + n2) * 16 + l15;                     \
            _Pragma("unroll")                                                   \
            for (int kk = 0; kk < 2; ++kk) {                                    \
                int j = (kk * 4 + l4) ^ (row & 7);                              \
                DST[n2][kk] = *(const bf16x8*)(Bls + row * 64 + j * 8);         \
            }                                                                   \
        }                                                                       \
    } while (0)
#define MFMA_QUAD(AF, BF, MI0, NI0)                                             \
    _Pragma("unroll")                                                           \
    for (int m2 = 0; m2 < 4; ++m2)                                              \
        _Pragma("unroll")                                                       \
        for (int n2 = 0; n2 < 2; ++n2)                                          \
            _Pragma("unroll")                                                   \
            for (int kk = 0; kk < 2; ++kk)                                      \
                acc[(MI0) + m2][(NI0) + n2] =                                   \
                    __builtin_amdgcn_mfma_f32_16x16x32_bf16(                    \
                        AF[m2][kk], BF[n2][kk], acc[(MI0) + m2][(NI0) + n2], 0, 0, 0);

    f32x4 acc[8][4] = {};

    const int T = GK / 64;   // 64 K-tiles
    STAGE_AQ(0, 0); STAGE_AQ(1, 0); STAGE_AQ(2, 0); STAGE_AQ(3, 0);
    STAGE_BS(0, 0); STAGE_BS(1, 0);
    STAGE_AQ(0, 1); STAGE_AQ(2, 1); STAGE_BS(0, 1);
    asm volatile("s_waitcnt vmcnt(4)" ::: "memory");
    __builtin_amdgcn_s_barrier();

    for (int t = 0; t < T; ++t) {
        const __bf16* Als = Asm + (t & 1) * 16384;
        const __bf16* Bls = (__bf16*)Bbase + (t & 1) * 16384;
        bf16x8 af0[4][2], af1[4][2], bA[2][2], bB[2][2];
        // ---- ph0: MH0 x NH0 ---- (af0 lives through ph1; bA through ph2)
        LOAD_A(af0, 0);
        LOAD_B(bA, 0);
        if (t + 1 < T) { STAGE_AQ(1, t + 1); STAGE_AQ(3, t + 1); }
        __builtin_amdgcn_s_barrier();
        __builtin_amdgcn_s_setprio(1);
        MFMA_QUAD(af0, bA, 0, 0);
        __builtin_amdgcn_s_setprio(0);
        __builtin_amdgcn_s_barrier();
        // ---- ph1: MH0 x NH1 ---- (bB lives through ph3)
        LOAD_B(bB, 1);
        if (t + 1 < T) STAGE_BS(1, t + 1);
        __builtin_amdgcn_s_barrier();
        __builtin_amdgcn_s_setprio(1);
        MFMA_QUAD(af0, bB, 0, 2);
        __builtin_amdgcn_s_setprio(0);
        __builtin_amdgcn_s_barrier();
        // ---- ph2: MH1 x NH0 ---- (reuse bA; no B reload)
        LOAD_A(af1, 1);
        if (t + 2 < T) { STAGE_AQ(0, t + 2); STAGE_AQ(2, t + 2); }
        __builtin_amdgcn_s_barrier();
        __builtin_amdgcn_s_setprio(1);
        MFMA_QUAD(af1, bA, 4, 0);
        __builtin_amdgcn_s_setprio(0);
        __builtin_amdgcn_s_barrier();
        // ---- ph3: MH1 x NH1 ---- (reuse bB; no ds_reads at all)
        if (t + 2 < T) STAGE_BS(0, t + 2);
        __builtin_amdgcn_s_barrier();
        __builtin_amdgcn_s_setprio(1);
        MFMA_QUAD(af1, bB, 4, 2);
        __builtin_amdgcn_s_setprio(0);
        if (t + 2 < T)      { asm volatile("s_waitcnt vmcnt(4)" ::: "memory"); }
        else if (t + 1 < T) { asm volatile("s_waitcnt vmcnt(0)" ::: "memory"); }
        __builtin_amdgcn_s_barrier();
    }
#undef MFMA_QUAD
#undef LOAD_A
#undef LOAD_B
#undef STAGE_AQ
#undef STAGE_BS

    if (MODE == 1) {
        if (n0 >= QSZ + KVSZ) {
            // V-slice block: write transposed into Vt [B*8, 128, S_LEN]
#pragma unroll
            for (int mi = 0; mi < 8; ++mi) {
                int s0 = m0 + wr * 128 + mi * 16 + l4 * 4;   // 4 consecutive tokens
                int b = s0 >> 11, s = s0 & 2047;
#pragma unroll
                for (int ni = 0; ni < 4; ++ni) {
                    int vcol = n0 - (QSZ + KVSZ) + wc * 64 + ni * 16 + l15;
                    int g = vcol >> 7, d = vcol & 127;
                    bf16x4 o4;
#pragma unroll
                    for (int r = 0; r < 4; ++r) o4[r] = (__bf16)acc[mi][ni][r];
                    *(bf16x4*)(Vt + ((size_t)((b * 8 + g) * HDIM + d)) * S_LEN + s) = o4;
                }
            }
        } else {
            // Q/K block: exchange through padded LDS (conflict-free), apply RoPE.
            __bf16* X = (__bf16*)Asm;   // [256][XPITCH]
            __syncthreads();
#pragma unroll
            for (int mi = 0; mi < 8; ++mi)
#pragma unroll
                for (int ni = 0; ni < 4; ++ni)
#pragma unroll
                    for (int r = 0; r < 4; ++r)
                        X[(wr * 128 + mi * 16 + l4 * 4 + r) * XPITCH
                          + wc * 64 + ni * 16 + l15] = (__bf16)acc[mi][ni][r];
            __syncthreads();
            const bool isQ = (n0 < QSZ);
#pragma unroll
            for (int it = 0; it < 16; ++it) {
                int idx = it * 512 + tid;        // 256 tok x 2 heads x 16 quads
                int q4 = (idx & 15) * 4;
                int hh = (idx >> 4) & 1;
                int lt = idx >> 5;
                int tok = m0 + lt;
                int bb = tok >> 11, ss = tok & 2047;
                int pp = pos[tok];
                float4 c4 = *(const float4*)(ct + (size_t)pp * 64 + q4);
                float4 s4 = *(const float4*)(st + (size_t)pp * 64 + q4);
                bf16x4 x1 = *(const bf16x4*)(X + lt * XPITCH + hh * 128 + q4);
                bf16x4 x2 = *(const bf16x4*)(X + lt * XPITCH + hh * 128 + 64 + q4);
                float cc[4] = {c4.x, c4.y, c4.z, c4.w};
                float sn[4] = {s4.x, s4.y, s4.z, s4.w};
                bf16x4 o1, o2;
                if (isQ) {
#pragma unroll
                    for (int k = 0; k < 4; ++k) {
                        float a = (float)x1[k], bv = (float)x2[k];
                        o1[k] = (__bf16)((a * cc[k] - bv * sn[k]) * ATT_SCALE);
                        o2[k] = (__bf16)((bv * cc[k] + a * sn[k]) * ATT_SCALE);
                    }
                    int gh = (n0 >> 7) + hh;
                    size_t o = ((size_t)(bb * 32 + gh) * S_LEN + ss) * HDIM + q4;
                    *(bf16x4*)(Qb + o)      = o1;
                    *(bf16x4*)(Qb + o + 64) = o2;
                } else {
#pragma unroll
                    for (int k = 0; k < 4; ++k) {
                        float a = (float)x1[k], bv = (float)x2[k];
                        o1[k] = (__bf16)(a * cc[k] - bv * sn[k]);
                        o2[k] = (__bf16)(bv * cc[k] + a * sn[k]);
                    }
                    int gk = ((n0 - QSZ) >> 7) + hh;
                    size_t o = ((size_t)(bb * 8 + gk) * S_LEN + ss) * HDIM + q4;
                    *(bf16x4*)(Kb + o)      = o1;
                    *(bf16x4*)(Kb + o + 64) = o2;
                }
            }
        }
    } else {
#pragma unroll
        for (int mi = 0; mi < 8; ++mi)
#pragma unroll
            for (int ni = 0; ni < 4; ++ni)
#pragma unroll
                for (int r = 0; r < 4; ++r)
                    C[(size_t)(m0 + wr * 128 + mi * 16 + l4 * 4 + r) * N
                      + n0 + wc * 64 + ni * 16 + l15] = (OUT)acc[mi][ni][r];
    }
}

// ---------------- Flash attention (causal, GQA rep=4) ----------------
// Paired q-tiles (qt=p and 7-p; grid 256 = one balanced round). QBLK=256
// (8 waves x 32 q-rows), KVBLK=64. Quad-buffered K/V (128KB LDS), depth-3
// counted vmcnt + raw barrier pairs. Swapped QK^T + swapped PV, in-register
// P transpose via permlane swaps.
__global__ __launch_bounds__(512, 2) void attn_kernel(const __bf16* __restrict__ Q,
                                                      const __bf16* __restrict__ K,
                                                      const __bf16* __restrict__ Vt,
                                                      __bf16* __restrict__ O) {
    const int tid = threadIdx.x;
    const int w = tid >> 6, l = tid & 63;
    const int l15 = l & 15, l4 = l >> 4;
    const int flat = blockIdx.x + (blockIdx.y << 2) + (blockIdx.z << 7);  // 0..255
    const int swz = (flat & 7) * 32 + (flat >> 3);
    const int p = swz & 3;
    const int hb = swz >> 2;
    const int h = hb & 31, b = hb >> 5;
    const int g = h >> 2;

    __shared__ __bf16 Ks[4][64 * 128];   // 4x16 KB; chunk c: row=c>>4, cc=(c&15)^(row&7)
    __shared__ __bf16 Vs[4][128 * 64];   // 4x16 KB; chunk c: row=c>>3, cc=(c&7)^(row&7)

    const __bf16* Kp = K + (size_t)(b * 8 + g) * S_LEN * HDIM;
    const __bf16* Vp = Vt + (size_t)(b * 8 + g) * HDIM * S_LEN;

#define RED16(x, OPINS) do {                                                      \
        u32 ra_ = __builtin_bit_cast(u32, x), rb_;                                \
        asm("v_mov_b32 %0, %1" : "=v"(rb_) : "v"(ra_));                           \
        asm("v_permlane16_swap_b32 %0, %1" : "+v"(ra_), "+v"(rb_));               \
        x = OPINS(__builtin_bit_cast(float, ra_), __builtin_bit_cast(float, rb_));\
    } while (0)
#define RED32(x, OPINS) do {                                                      \
        u32 ra_ = __builtin_bit_cast(u32, x), rb_;                                \
        asm("v_mov_b32 %0, %1" : "=v"(rb_) : "v"(ra_));                           \
        asm("v_permlane32_swap_b32 %0, %1" : "+v"(ra_), "+v"(rb_));               \
        x = OPINS(__builtin_bit_cast(float, ra_), __builtin_bit_cast(float, rb_));\
    } while (0)
#define FADD_(a_, b_) ((a_) + (b_))

#define STAGE(ktile) do {                                                          \
        const int buf_ = (ktile) & 3;                                              \
        const __bf16* kbase = Kp + (size_t)(ktile) * 64 * HDIM;                    \
        _Pragma("unroll")                                                          \
        for (int i_ = 0; i_ < 2; ++i_) {                                           \
            int c_ = i_ * 512 + tid;            /* 1024 chunks = 64x128 bf16 */    \
            int row_ = c_ >> 4, cc_ = (c_ & 15) ^ (row_ & 7);                      \
            GLDS16(kbase + (size_t)row_ * HDIM + cc_ * 8,                          \
                   (char*)Ks[buf_] + c_ * 16);                                     \
        }                                                                          \
        const __bf16* vbase = Vp + (size_t)(ktile) * 64;                           \
        _Pragma("unroll")                                                          \
        for (int i_ = 0; i_ < 2; ++i_) {                                           \
            int c_ = i_ * 512 + tid;            /* 1024 chunks = 128x64 bf16 */    \
            int row_ = c_ >> 3, cc_ = (c_ & 7) ^ (row_ & 7);                       \
            GLDS16(vbase + (size_t)row_ * S_LEN + cc_ * 8,                         \
                   (char*)Vs[buf_] + c_ * 16);                                     \
        }                                                                          \
    } while (0)

    for (int pi = 0; pi < 2; ++pi) {
        const int qt = pi ? (7 - p) : p;
        const int qw0 = qt * 256 + w * 32;       // wave's first q-row
        const __bf16* Qp = Q + ((size_t)((b * 32 + h) * S_LEN + qw0)) * HDIM;

        bf16x8 qf[2][4];
#pragma unroll
        for (int qh = 0; qh < 2; ++qh)
#pragma unroll
            for (int kk = 0; kk < 4; ++kk)
                qf[qh][kk] = *(const bf16x8*)(Qp + (size_t)(qh * 16 + l15) * HDIM + kk * 32 + l4 * 8);

        f32x4 acc[2][8] = {};   // [qh][n]: D[d = n*16 + l4*4 + r][q = qw0+qh*16+l15]
        float m[2]    = {-1e30f, -1e30f};
        float lsum[2] = {0.f, 0.f};

        const int nkt = 4 * qt + 4;
        // pass-2 entry: retire pass-1 epilogue stores so counted vmcnt stays exact
        if (pi) { asm volatile("s_waitcnt vmcnt(0)" ::: "memory"); }
        STAGE(0);
        STAGE(1);
        STAGE(2);

        for (int kt = 0; kt < nkt; ++kt) {
            if (kt + 3 < nkt) STAGE(kt + 3);
            {
                int rem = nkt - 1 - kt;
                if (rem >= 3)      { asm volatile("s_waitcnt vmcnt(12)" ::: "memory"); }
                else if (rem == 2) { asm volatile("s_waitcnt vmcnt(8)"  ::: "memory"); }
                else if (rem == 1) { asm volatile("s_waitcnt vmcnt(4)"  ::: "memory"); }
                else               { asm volatile("s_waitcnt vmcnt(0)"  ::: "memory"); }
            }
            __builtin_amdgcn_sched_barrier(0);
            __builtin_amdgcn_s_barrier();      // barrier#1: tile kt visible to all
            __builtin_amdgcn_sched_barrier(0);
            const int cur = kt & 3;
            if (kt * 64 <= qw0 + 31) {         // wave-level causal skip
                f32x4 sfr[2][4];
                __builtin_amdgcn_s_setprio(1);
#pragma unroll
                for (int fn = 0; fn < 4; ++fn) {
                    f32x4 sa0 = {}, sa1 = {};
#pragma unroll
                    for (int kk = 0; kk < 4; ++kk) {
                        int row = fn * 16 + l15;
                        int cc = (kk * 4 + l4) ^ (l15 & 7);
                        bf16x8 kb = *(const bf16x8*)(Ks[cur] + row * HDIM + cc * 8);
                        sa0 = __builtin_amdgcn_mfma_f32_16x16x32_bf16(kb, qf[0][kk], sa0, 0, 0, 0);
                        sa1 = __builtin_amdgcn_mfma_f32_16x16x32_bf16(kb, qf[1][kk], sa1, 0, 0, 0);
                    }
                    sfr[0][fn] = sa0; sfr[1][fn] = sa1;
                }
                __builtin_amdgcn_s_setprio(0);
                const bool needmask = (kt * 64 + 63 > qw0);
                bf16x8 pb[2][2];
#pragma unroll
                for (int qh = 0; qh < 2; ++qh) {
                    const int qrow = qw0 + qh * 16 + l15;
                    float pmax = -1e30f;
#pragma unroll
                    for (int fn = 0; fn < 4; ++fn)
#pragma unroll
                        for (int r = 0; r < 4; ++r) {
                            float v = sfr[qh][fn][r];
                            if (needmask) {
                                int kcol = kt * 64 + fn * 16 + l4 * 4 + r;
                                if (kcol > qrow) v = -1e30f;
                            }
                            sfr[qh][fn][r] = v;
                            pmax = fmaxf(pmax, v);
                        }
                    RED16(pmax, fmaxf);
                    RED32(pmax, fmaxf);
                    if (!__all(pmax - m[qh] <= 8.0f)) {          // defer-max (rare)
                        float mn = fmaxf(m[qh], pmax);
                        float alpha = exp2f((m[qh] - mn) * L2E);
                        m[qh] = mn;
                        lsum[qh] *= alpha;
#pragma unroll
                        for (int n = 0; n < 8; ++n)
#pragma unroll
                            for (int r = 0; r < 4; ++r) acc[qh][n][r] *= alpha;
                    }
                    float rs = 0.f;
                    u32 pk01[4], pk23[4];
#pragma unroll
                    for (int fn = 0; fn < 4; ++fn) {
                        float p0 = exp2f((sfr[qh][fn][0] - m[qh]) * L2E);
                        float p1 = exp2f((sfr[qh][fn][1] - m[qh]) * L2E);
                        float p2 = exp2f((sfr[qh][fn][2] - m[qh]) * L2E);
                        float p3 = exp2f((sfr[qh][fn][3] - m[qh]) * L2E);
                        rs += (p0 + p1) + (p2 + p3);
                        asm("v_cvt_pk_bf16_f32 %0, %1, %2" : "=v"(pk01[fn]) : "v"(p0), "v"(p1));
                        asm("v_cvt_pk_bf16_f32 %0, %1, %2" : "=v"(pk23[fn]) : "v"(p2), "v"(p3));
                    }
                    RED16(rs, FADD_);
                    RED32(rs, FADD_);
                    lsum[qh] += rs;
#pragma unroll
                    for (int kk = 0; kk < 2; ++kk) {
                        u32 w0 = pk01[2 * kk], w2 = pk01[2 * kk + 1];
                        asm("v_permlane32_swap_b32 %0, %1" : "+v"(w0), "+v"(w2));
                        asm("v_permlane16_swap_b32 %0, %1" : "+v"(w0), "+v"(w2));
                        u32 w1 = pk23[2 * kk], w3 = pk23[2 * kk + 1];
                        asm("v_permlane32_swap_b32 %0, %1" : "+v"(w1), "+v"(w3));
                        asm("v_permlane16_swap_b32 %0, %1" : "+v"(w1), "+v"(w3));
                        u32x4 wv;
                        wv[0] = w0; wv[1] = w1; wv[2] = w2; wv[3] = w3;
                        pb[qh][kk] = __builtin_bit_cast(bf16x8, wv);
                    }
                }
                __builtin_amdgcn_s_setprio(1);
#pragma unroll
                for (int kk = 0; kk < 2; ++kk) {
#pragma unroll
                    for (int n = 0; n < 8; ++n) {
                        int row = n * 16 + l15;
                        int cc = (kk * 4 + l4) ^ (l15 & 7);
                        bf16x8 vb = *(const bf16x8*)(Vs[cur] + row * 64 + cc * 8);
                        acc[0][n] = __builtin_amdgcn_mfma_f32_16x16x32_bf16(vb, pb[0][kk], acc[0][n], 0, 0, 0);
                        acc[1][n] = __builtin_amdgcn_mfma_f32_16x16x32_bf16(vb, pb[1][kk], acc[1][n], 0, 0, 0);
                    }
                }
                __builtin_amdgcn_s_setprio(0);
            }
            __builtin_amdgcn_sched_barrier(0);
            __builtin_amdgcn_s_barrier();      // barrier#2: reads of slot kt done
            __builtin_amdgcn_sched_barrier(0);
        }
        // ---- epilogue: attn[b, q, h*128 + d], d = n*16 + l4*4 + r ----
#pragma unroll
        for (int qh = 0; qh < 2; ++qh) {
            float inv = 1.0f / lsum[qh];
            int qrow = qw0 + qh * 16 + l15;
            __bf16* obase = O + ((size_t)(b * S_LEN) + qrow) * QSZ + h * HDIM + l4 * 4;
#pragma unroll
            for (int n = 0; n < 8; ++n) {
                bf16x4 o4;
#pragma unroll
                for (int r = 0; r < 4; ++r) o4[r] = (__bf16)(acc[qh][n][r] * inv);
                *(bf16x4*)(obase + n * 16) = o4;
            }
        }
    }
#undef STAGE
#undef RED16
#undef RED32
#undef FADD_
}

extern "C" void kernel_launch(void* const* d_in, const int* in_sizes, int n_in,
                              void* d_out, int out_size, void* d_ws, size_t ws_size,
                              hipStream_t stream) {
    const int*   pos    = (const int*)d_in[0];
    const float* hidden = (const float*)d_in[1];
    const float* wqkv   = (const float*)d_in[2];
    const float* wo     = (const float*)d_in[3];
    float* out = (float*)d_out;

    // workspace carve
    __bf16* hb    = (__bf16*)d_ws;                     // 16,777,216 elems
    __bf16* wqb   = hb  + 16777216;                    // 25,165,824
    __bf16* wob   = wqb + 25165824;                    // 16,777,216
    __bf16* Qb    = wob + 16777216;                    // 16,777,216
    __bf16* Kb    = Qb  + 16777216;                    // 4,194,304
    __bf16* Vtb   = Kb  + 4194304;                     // 4,194,304
    __bf16* attnb = Vtb + 4194304;                     // 16,777,216
    float*  rc    = (float*)(attnb + 16777216);        // 131,072
    float*  rs    = rc + 131072;                       // 131,072

    prep_kernel<<<2048, 256, 0, stream>>>(hidden, hb, 4194304,
                                          wqkv, wqb, 6291456,
                                          wo, wob, 4194304, rc, rs);
    // fused QKV GEMM: V blocks -> Vtb (transposed); Q/K blocks -> RoPE -> Qb/Kb
    gemm256<__bf16, 1><<<dim3(QKVSZ / 256, (B_DIM * S_LEN) / 256), 512, 0, stream>>>(
        hb, wqb, ((__bf16*)nullptr), Vtb, Qb, Kb, pos, rc, rs, QKVSZ);
    attn_kernel<<<dim3(4, NHEADS, B_DIM), 512, 0, stream>>>(Qb, Kb, Vtb, attnb);
    gemm256<float, 0><<<dim3(HIDDEN / 256, (B_DIM * S_LEN) / 256), 512, 0, stream>>>(
        attnb, wob, out, nullptr, nullptr, nullptr, nullptr, nullptr, nullptr, HIDDEN);
}